// Round 6
// baseline (990.295 us; speedup 1.0000x reference)
//
#include <hip/hip_runtime.h>

// Problem constants: B=4, S=2048, HIDDEN=1024, NH=16, HD=64
#define SEQ    2048
#define BATCH  4
#define HID    1024
#define NH     16
#define MTOT   (BATCH * SEQ)   // 8192

typedef __attribute__((ext_vector_type(8)))  short          short8;   // 8 bf16 frag
typedef __attribute__((ext_vector_type(4)))  float          f32x4;
typedef __attribute__((ext_vector_type(16))) float          f32x16;   // 32x32 C/D
typedef __attribute__((ext_vector_type(8)))  unsigned short ushort8v;
typedef __attribute__((ext_vector_type(4)))  unsigned int   uint4v;

#define QSCL 0.125f   // 1/sqrt(64); __expf supplies the log2e internally

__device__ __forceinline__ float bf2f(unsigned short u) {
    return __uint_as_float(((unsigned int)u) << 16);
}
__device__ __forceinline__ unsigned short f2bf(float f) {
    unsigned int u = __float_as_uint(f);
    u += 0x7fffu + ((u >> 16) & 1u);   // RNE
    return (unsigned short)(u >> 16);
}
// pack two fp32 -> two bf16 (round-half-up) in one uint
__device__ __forceinline__ unsigned int pk2bf(float lo, float hi) {
    unsigned int ul = __float_as_uint(lo) + 0x8000u;
    unsigned int uh = __float_as_uint(hi) + 0x8000u;
    return __builtin_amdgcn_perm(uh, ul, 0x07060302u);
}

// async global->LDS, 16B per lane (global_load_lds_dwordx4)
__device__ __forceinline__ void gl_lds16(const void* g, void* l) {
    __builtin_amdgcn_global_load_lds(
        (__attribute__((address_space(1))) void*)g,
        (__attribute__((address_space(3))) void*)l, 16, 0, 0);
}

// XOR swizzle on 8-element (16B) groups for [*][64] tiles (8 slots/row)
__device__ __forceinline__ int swz64(int row, int col) {
    return row * 64 + ((((col >> 3) ^ (row & 7))) << 3) + (col & 7);
}

// GEMM BK=64 granule layout: granule (row,kq) of a [128][64] bf16 tile at
// ushort offset (row*8 + ((kq + (row&7)) & 7)) * 8.
__device__ __forceinline__ int gidx64(int row, int kq) {
    return (row * 8 + ((kq + (row & 7)) & 7)) * 8;
}

// ===========================================================================
// x fp32 -> bf16 (to d_out scratch). 4 elems/thread.
// ===========================================================================
__global__ __launch_bounds__(256)
void cvt_x(const float* __restrict__ x, unsigned short* __restrict__ xb)
{
    const size_t i = ((size_t)blockIdx.x * 256 + threadIdx.x) * 4;
    const float4 f = *(const float4*)(x + i);
    uint2 u;
    u.x = pk2bf(f.x, f.y);
    u.y = pk2bf(f.z, f.w);
    *(uint2*)(xb + i) = u;
}

// ===========================================================================
// Weight transpose + fp32->bf16: Wt[N][K] = bf16(W[K][N])
// ===========================================================================
__global__ __launch_bounds__(256)
void transpose_cvt(const float* __restrict__ W, unsigned short* __restrict__ Wt,
                   int K, int N)
{
    __shared__ unsigned short T[32][33];
    const int n0 = blockIdx.x * 32, k0 = blockIdx.y * 32;
    const int tr = threadIdx.x >> 3, tc = (threadIdx.x & 7) * 4;
    const float4 f = *(const float4*)(W + (size_t)(k0 + tr) * N + n0 + tc);
    T[tr][tc + 0] = f2bf(f.x);
    T[tr][tc + 1] = f2bf(f.y);
    T[tr][tc + 2] = f2bf(f.z);
    T[tr][tc + 3] = f2bf(f.w);
    __syncthreads();
    ushort4 u;
    u.x = T[tc + 0][tr]; u.y = T[tc + 1][tr];
    u.z = T[tc + 2][tr]; u.w = T[tc + 3][tr];
    *(ushort4*)(Wt + (size_t)(n0 + tr) * K + k0 + tc) = u;
}

// ===========================================================================
// MFMA GEMM, 128x128 tile, BK=64, async global_load_lds staging.
// A bf16 [M][lda]; B transposed bf16 Bt[N][K].
// VSPLIT (qk gemm, N=2048): cols [0,1024) q -> *QSCL bf16; rest k -> bf16.
// BIASROW (v gemm): bias indexed by ROW (C = Wv^T x^T), bf16 C.
// Else: fp32 (OUTF32) or bf16 C.
// ===========================================================================
template<bool OUTF32, bool VSPLIT, bool BIASROW>
__global__ __launch_bounds__(256)
void gemm_mfma(const unsigned short* __restrict__ A,
               const unsigned short* __restrict__ Bt,
               const float* __restrict__ bias, void* __restrict__ Cptr,
               int lda, int ldc, int K)
{
    __shared__ unsigned short As[128 * 64];   // 16 KB
    __shared__ unsigned short Bs[128 * 64];   // 16 KB

    const int tid = threadIdx.x;
    const int wave = tid >> 6, lane = tid & 63;
    const int quad = lane >> 4, lm = lane & 15;
    const int wm = wave & 1, wn = wave >> 1;
    const int m0 = blockIdx.y * 128, n0 = blockIdx.x * 128;

    // staging pointers: 4 granules per thread per matrix per K-step
    const unsigned short* aSrc[4];
    const unsigned short* bSrc[4];
    unsigned short* aDst[4];
    unsigned short* bDst[4];
    #pragma unroll
    for (int j = 0; j < 4; ++j) {
        const int g = (wave * 4 + j) * 64 + lane;   // granule 0..1023
        const int row = g >> 3;
        const int kq = ((g & 7) - (row & 7)) & 7;
        aSrc[j] = A  + (size_t)(m0 + row) * lda + kq * 8;
        bSrc[j] = Bt + (size_t)(n0 + row) * K   + kq * 8;
        aDst[j] = &As[g * 8];
        bDst[j] = &Bs[g * 8];
    }

    f32x4 acc[4][4];
    #pragma unroll
    for (int i = 0; i < 4; ++i)
        #pragma unroll
        for (int j = 0; j < 4; ++j)
            acc[i][j] = (f32x4){0.f, 0.f, 0.f, 0.f};

    // fragment LDS offsets (2 k-halves x 4 tiles), conflict-free
    int aOff[2][4], bOff[2][4];
    #pragma unroll
    for (int h = 0; h < 2; ++h)
        #pragma unroll
        for (int i = 0; i < 4; ++i) {
            aOff[h][i] = gidx64(wm * 64 + i * 16 + lm, h * 4 + quad);
            bOff[h][i] = gidx64(wn * 64 + i * 16 + lm, h * 4 + quad);
        }

    for (int k0 = 0; k0 < K; k0 += 64) {
        __syncthreads();                    // prev consumers done
        #pragma unroll
        for (int j = 0; j < 4; ++j) gl_lds16(aSrc[j] + k0, aDst[j]);
        #pragma unroll
        for (int j = 0; j < 4; ++j) gl_lds16(bSrc[j] + k0, bDst[j]);
        __syncthreads();                    // DMA visible

        #pragma unroll
        for (int h = 0; h < 2; ++h) {
            short8 af[4], bf[4];
            #pragma unroll
            for (int i = 0; i < 4; ++i) af[i] = *(const short8*)&As[aOff[h][i]];
            #pragma unroll
            for (int j = 0; j < 4; ++j) bf[j] = *(const short8*)&Bs[bOff[h][j]];
            #pragma unroll
            for (int i = 0; i < 4; ++i)
                #pragma unroll
                for (int j = 0; j < 4; ++j)
                    acc[i][j] = __builtin_amdgcn_mfma_f32_16x16x32_bf16(
                        af[i], bf[j], acc[i][j], 0, 0, 0);
        }
    }

    float bj[4];        // per-col bias (normal)
    float br[4][4];     // per-row bias (BIASROW): [i][rr]
    if constexpr (BIASROW) {
        #pragma unroll
        for (int i = 0; i < 4; ++i) {
            const float4 t =
                *(const float4*)(bias + m0 + wm * 64 + i * 16 + quad * 4);
            br[i][0] = t.x; br[i][1] = t.y; br[i][2] = t.z; br[i][3] = t.w;
        }
    } else {
        #pragma unroll
        for (int j = 0; j < 4; ++j) bj[j] = bias[n0 + wn * 64 + j * 16 + lm];
    }

    #pragma unroll
    for (int i = 0; i < 4; ++i) {
        #pragma unroll
        for (int j = 0; j < 4; ++j) {
            const int col = n0 + wn * 64 + j * 16 + lm;
            #pragma unroll
            for (int rr = 0; rr < 4; ++rr) {
                const int row = m0 + wm * 64 + i * 16 + quad * 4 + rr;
                float v = acc[i][j][rr] + (BIASROW ? br[i][rr] : bj[j]);
                if constexpr (VSPLIT) {
                    if (col < 1024) v *= QSCL;   // q pre-scale
                    ((unsigned short*)Cptr)[(size_t)row * ldc + col] = f2bf(v);
                } else if constexpr (OUTF32) {
                    ((float*)Cptr)[(size_t)row * ldc + col] = v;
                } else {
                    ((unsigned short*)Cptr)[(size_t)row * ldc + col] = f2bf(v);
                }
            }
        }
    }
}

// ===========================================================================
// MFMA flash attention v8: 8-wave (512-thread) blocks = 4 q-waves x 2
// kv-halves. Grid unchanged (512 blocks) but waves/SIMD 2 -> 4: the ~55%
// dependency-stall fraction seen across v5/v6/v7 (all 101-102 us, MfmaUtil
// 28 / VALUBusy 46 / Occ 18) gets hidden by 2x more resident waves.
// Per-wave compute is byte-identical to v7 (KVBLK=64, in-register P via
// T12, swz64 K/V, gl_lds dbuf staging with pre-swizzled source); each wave
// covers HALF the kv range (16 tiles, sequential), partials combined once
// through LDS: O = (O_h0 + O_h1) / (l_h0 + l_h1).
// LDS: dbuf x 2 halves x (K+V) = 64 KB, overlaid by the f32 combine buffer
// (dead after last barrier). 2 blocks/CU (66 KB). VGPR capped 128 by
// __launch_bounds__(512,4) -- no spill (watch WRITE_SIZE; round-4 lesson).
// ===========================================================================
__global__ __launch_bounds__(512, 4)
void attn_mfma(unsigned short* __restrict__ qk,
               const unsigned short* __restrict__ Vt)
{
    const int qt = blockIdx.x, hh = blockIdx.y, b = blockIdx.z;
    const size_t row0 = (size_t)b * SEQ;
    const int tid = threadIdx.x;
    const int wave = tid >> 6, lane = tid & 63;
    const int wq = wave & 3;          // q-tile within block
    const int kh = wave >> 2;         // kv half (0: kt 0..1023, 1: 1024..2047)
    const int l5 = lane >> 5, lm = lane & 31;

    __shared__ union {
        struct {
            unsigned short Ks[2][2][64 * 64];   // [buf][half][kvpos][d] swz64
            unsigned short Vs[2][2][64 * 64];   // [buf][half][d][kvpos] swz64
        } t;                                    // 64 KB
        float Ocmb[4][64][64];                  // [wq][frag][lane] f32 partials
    } u;
    __shared__ float Lcmb[4][2][64];            // [wq][qg][lane]

    const int qbase = qt * 256 + wq * 64;

    short8 qf[2][4];
    #pragma unroll
    for (int qg = 0; qg < 2; ++qg)
        #pragma unroll
        for (int ks = 0; ks < 4; ++ks)
            qf[qg][ks] = *(const short8*)(
                qk + (row0 + qbase + qg * 32 + lm) * 2048 + hh * 64 + ks * 16 + l5 * 8);

    f32x16 oacc[2][2];
    #pragma unroll
    for (int dg = 0; dg < 2; ++dg)
        #pragma unroll
        for (int qg = 0; qg < 2; ++qg)
            #pragma unroll
            for (int e = 0; e < 16; ++e) oacc[dg][qg][e] = 0.f;
    float lrun[2] = {0.f, 0.f};

    // DMA staging: per step stage 4 matrices (K,V for both halves), 512
    // granules each; thread (wave,lane) owns granule g = wave*64+lane of
    // every matrix. row=g>>3, slot=g&7, src col-group = slot^(row&7)
    // (inverse of the swz64 read involution; LDS dest is linear).
    const int g    = wave * 64 + lane;
    const int grow = g >> 3, gslot = g & 7;
    const int colg = gslot ^ (grow & 7);
    const int dOff = g * 8;
    // K source for half h: kv row = h*1024 + step*64 + grow
    const unsigned short* kSrcH[2];
    const unsigned short* vSrcH[2];
    #pragma unroll
    for (int h = 0; h < 2; ++h) {
        kSrcH[h] = qk + 1024 + hh * 64 + (row0 + h * 1024 + grow) * 2048 + colg * 8;
        vSrcH[h] = Vt + (size_t)(hh * 64 + grow) * (size_t)MTOT
                      + (size_t)b * SEQ + h * 1024 + colg * 8;
    }

    // prologue: stage step 0 into buffer 0
    #pragma unroll
    for (int h = 0; h < 2; ++h) {
        gl_lds16(kSrcH[h], &u.t.Ks[0][h][dOff]);
        gl_lds16(vSrcH[h], &u.t.Vs[0][h][dOff]);
    }
    __syncthreads();   // drains DMA before first reads

    int cur = 0;
    for (int st = 0; st < 16; ++st) {
        if (st + 1 < 16) {   // issue next step's DMA into the other buffer
            const size_t ko = (size_t)((st + 1) * 64) * 2048;
            const int vo = (st + 1) * 64;
            #pragma unroll
            for (int h = 0; h < 2; ++h) {
                gl_lds16(kSrcH[h] + ko, &u.t.Ks[cur ^ 1][h][dOff]);
                gl_lds16(vSrcH[h] + vo, &u.t.Vs[cur ^ 1][h][dOff]);
            }
        }
        const unsigned short* ksc = u.t.Ks[cur][kh];
        const unsigned short* vsc = u.t.Vs[cur][kh];

        #pragma unroll
        for (int kg = 0; kg < 2; ++kg) {
            short8 aK[4];
            #pragma unroll
            for (int ks = 0; ks < 4; ++ks)
                aK[ks] = *(const short8*)&ksc[swz64(kg * 32 + lm, ks * 16 + l5 * 8)];

            // QK^T (swapped: rows = k, cols = q) then exp, all in-register.
            f32x16 s[2];
            #pragma unroll
            for (int qg = 0; qg < 2; ++qg) {
                #pragma unroll
                for (int e = 0; e < 16; ++e) s[qg][e] = 0.f;
                __builtin_amdgcn_s_setprio(1);
                #pragma unroll
                for (int ks = 0; ks < 4; ++ks)
                    s[qg] = __builtin_amdgcn_mfma_f32_32x32x16_bf16(
                        aK[ks], qf[qg][ks], s[qg], 0, 0, 0);
                __builtin_amdgcn_s_setprio(0);
                float ls = 0.f;
                #pragma unroll
                for (int rg = 0; rg < 4; ++rg) {
                    const float p0 = __expf(s[qg][rg * 4 + 0]);
                    const float p1 = __expf(s[qg][rg * 4 + 1]);
                    const float p2 = __expf(s[qg][rg * 4 + 2]);
                    const float p3 = __expf(s[qg][rg * 4 + 3]);
                    s[qg][rg * 4 + 0] = p0; s[qg][rg * 4 + 1] = p1;
                    s[qg][rg * 4 + 2] = p2; s[qg][rg * 4 + 3] = p3;
                    ls += (p0 + p1) + (p2 + p3);
                }
                lrun[qg] += ls;
            }

            // PV: build B-fragment in-register (T12).
            // s[qg] reg r holds P[row = kg*32 + (r&3)+8*(r>>2)+4*l5][q=lm].
            #pragma unroll
            for (int step = 0; step < 2; ++step) {
                const int ks = kg * 2 + step;
                const short8 aV0 =
                    *(const short8*)&vsc[swz64(lm,      ks * 16 + l5 * 8)];
                const short8 aV1 =
                    *(const short8*)&vsc[swz64(32 + lm, ks * 16 + l5 * 8)];
                #pragma unroll
                for (int qg = 0; qg < 2; ++qg) {
                    const int b0 = step * 8;
                    const unsigned int uu = pk2bf(s[qg][b0 + 0], s[qg][b0 + 1]);
                    const unsigned int vv = pk2bf(s[qg][b0 + 2], s[qg][b0 + 3]);
                    const unsigned int u2 = pk2bf(s[qg][b0 + 4], s[qg][b0 + 5]);
                    const unsigned int v2 = pk2bf(s[qg][b0 + 6], s[qg][b0 + 7]);
                    const auto rA =
                        __builtin_amdgcn_permlane32_swap(uu, u2, false, false);
                    const auto rB =
                        __builtin_amdgcn_permlane32_swap(vv, v2, false, false);
                    uint4v wv;
                    wv.x = rA[0]; wv.y = rB[0]; wv.z = rA[1]; wv.w = rB[1];
                    const short8 bP = __builtin_bit_cast(short8, wv);
                    __builtin_amdgcn_s_setprio(1);
                    oacc[0][qg] = __builtin_amdgcn_mfma_f32_32x32x16_bf16(
                        aV0, bP, oacc[0][qg], 0, 0, 0);
                    oacc[1][qg] = __builtin_amdgcn_mfma_f32_32x32x16_bf16(
                        aV1, bP, oacc[1][qg], 0, 0, 0);
                    __builtin_amdgcn_s_setprio(0);
                }
            }
        }
        __syncthreads();   // readers of cur done; next-step DMA drained
        cur ^= 1;
    }

    // ---- combine halves through LDS (K/V buffers are dead past the last
    //      barrier; no DMA in flight for step 16) ----
    if (kh == 1) {
        #pragma unroll
        for (int dg = 0; dg < 2; ++dg)
            #pragma unroll
            for (int qg = 0; qg < 2; ++qg)
                #pragma unroll
                for (int e = 0; e < 16; ++e)
                    u.Ocmb[wq][(dg * 2 + qg) * 16 + e][lane] = oacc[dg][qg][e];
        Lcmb[wq][0][lane] = lrun[0];
        Lcmb[wq][1][lane] = lrun[1];
    }
    __syncthreads();
    if (kh == 0) {
        #pragma unroll
        for (int dg = 0; dg < 2; ++dg)
            #pragma unroll
            for (int qg = 0; qg < 2; ++qg)
                #pragma unroll
                for (int e = 0; e < 16; ++e)
                    oacc[dg][qg][e] += u.Ocmb[wq][(dg * 2 + qg) * 16 + e][lane];
        lrun[0] += Lcmb[wq][0][lane];
        lrun[1] += Lcmb[wq][1][lane];

        float linv[2];
        #pragma unroll
        for (int qg = 0; qg < 2; ++qg) {
            const float lt = lrun[qg] + __shfl_xor(lrun[qg], 32);
            linv[qg] = 1.f / lt;
        }

        #pragma unroll
        for (int dg = 0; dg < 2; ++dg)
            #pragma unroll
            for (int qg = 0; qg < 2; ++qg) {
                unsigned short* orow =
                    qk + (row0 + qbase + qg * 32 + lm) * 2048 + hh * 64;
                #pragma unroll
                for (int rg = 0; rg < 4; ++rg) {
                    const int d0 = dg * 32 + rg * 8 + l5 * 4;
                    ushort4 st;
                    st.x = f2bf(oacc[dg][qg][rg * 4 + 0] * linv[qg]);
                    st.y = f2bf(oacc[dg][qg][rg * 4 + 1] * linv[qg]);
                    st.z = f2bf(oacc[dg][qg][rg * 4 + 2] * linv[qg]);
                    st.w = f2bf(oacc[dg][qg][rg * 4 + 3] * linv[qg]);
                    *(ushort4*)(orow + d0) = st;
                }
            }
    }
}

// ===========================================================================
// ================= FALLBACK PATH (round-4, verified PASS) ==================
// ===========================================================================
__global__ __launch_bounds__(256)
void qproj(const float* __restrict__ A, const float* __restrict__ W,
           const float* __restrict__ bias, unsigned short* __restrict__ outus)
{
    __shared__ float As[64][17];
    __shared__ float Bs[16][64];
    const int tid = threadIdx.x;
    const int tx = tid & 15, ty = tid >> 4;
    const int m0 = blockIdx.y * 64, n0 = blockIdx.x * 64;
    const int ar = tid >> 2, ac = (tid & 3) * 4;
    const int br = tid >> 4, bc = (tid & 15) * 4;
    float acc[4][4] = {{0.f}};
    for (int k0 = 0; k0 < HID; k0 += 16) {
        const float4 av = *(const float4*)(A + (size_t)(m0 + ar) * HID + k0 + ac);
        As[ar][ac + 0] = av.x; As[ar][ac + 1] = av.y;
        As[ar][ac + 2] = av.z; As[ar][ac + 3] = av.w;
        *(float4*)&Bs[br][bc] =
            *(const float4*)(W + (size_t)(k0 + br) * 3072 + n0 + bc);
        __syncthreads();
        #pragma unroll
        for (int kk = 0; kk < 16; ++kk) {
            float a[4];
            #pragma unroll
            for (int i = 0; i < 4; ++i) a[i] = As[ty * 4 + i][kk];
            const float4 b4 = *(const float4*)&Bs[kk][tx * 4];
            const float bv[4] = {b4.x, b4.y, b4.z, b4.w};
            #pragma unroll
            for (int i = 0; i < 4; ++i)
                #pragma unroll
                for (int j = 0; j < 4; ++j)
                    acc[i][j] = fmaf(a[i], bv[j], acc[i][j]);
        }
        __syncthreads();
    }
    float bb[4];
    #pragma unroll
    for (int j = 0; j < 4; ++j) bb[j] = bias[n0 + tx * 4 + j];
    #pragma unroll
    for (int i = 0; i < 4; ++i) {
        ushort4 st;
        st.x = f2bf(acc[i][0] + bb[0]); st.y = f2bf(acc[i][1] + bb[1]);
        st.z = f2bf(acc[i][2] + bb[2]); st.w = f2bf(acc[i][3] + bb[3]);
        *(ushort4*)(outus + (size_t)(m0 + ty * 4 + i) * 2048 + 1024 + n0 + tx * 4) = st;
    }
}

__global__ __launch_bounds__(256)
void kv_inplace(const float* __restrict__ W, const float* __restrict__ bias,
                unsigned short* __restrict__ xu)
{
    const float* xf = (const float*)xu;
    __shared__ unsigned short Asb[16][1032];
    __shared__ float Bs[16][68];
    const int tid = threadIdx.x;
    const int m0 = blockIdx.x * 16;
    const int tx = tid & 15, ty = tid >> 4;
    #pragma unroll 4
    for (int i = 0; i < 16; ++i) {
        const float4 v = *(const float4*)(xf + (size_t)(m0 + i) * HID + tid * 4);
        ushort4 s;
        s.x = f2bf(v.x); s.y = f2bf(v.y); s.z = f2bf(v.z); s.w = f2bf(v.w);
        *(ushort4*)&Asb[i][tid * 4] = s;
    }
    __syncthreads();
    for (int n0 = 0; n0 < 2048; n0 += 64) {
        float acc[4] = {0.f, 0.f, 0.f, 0.f};
        for (int k0 = 0; k0 < HID; k0 += 16) {
            *(float4*)&Bs[ty][tx * 4] =
                *(const float4*)(W + (size_t)(k0 + ty) * 3072 + 1024 + n0 + tx * 4);
            __syncthreads();
            #pragma unroll
            for (int kk = 0; kk < 16; ++kk) {
                const float a = bf2f(Asb[ty][k0 + kk]);
                const float4 b4 = *(const float4*)&Bs[kk][tx * 4];
                acc[0] = fmaf(a, b4.x, acc[0]); acc[1] = fmaf(a, b4.y, acc[1]);
                acc[2] = fmaf(a, b4.z, acc[2]); acc[3] = fmaf(a, b4.w, acc[3]);
            }
            __syncthreads();
        }
        const int n = n0 + tx * 4;
        ushort4 s;
        s.x = f2bf(acc[0] + bias[1024 + n + 0]);
        s.y = f2bf(acc[1] + bias[1024 + n + 1]);
        s.z = f2bf(acc[2] + bias[1024 + n + 2]);
        s.w = f2bf(acc[3] + bias[1024 + n + 3]);
        *(ushort4*)(xu + (size_t)(m0 + ty) * 2048 + n) = s;
    }
}

__global__ __launch_bounds__(256)
void attn_fwd(const unsigned short* __restrict__ xu,
              unsigned short* __restrict__ outus)
{
    const int qt = blockIdx.x, h = blockIdx.y, b = blockIdx.z;
    const int s0 = qt * 16;
    const size_t row0 = (size_t)b * SEQ;
    const int tid = threadIdx.x;
    const int qi = tid >> 4, tj = tid & 15;
    __shared__ float Ksh[64][68];
    __shared__ float Vsh[64][68];
    __shared__ float Psh[16][68];
    float qreg[64];
    {
        const uint4* qp =
            (const uint4*)(outus + (row0 + s0 + qi) * 2048 + 1024 + h * 64);
        #pragma unroll
        for (int i = 0; i < 8; ++i) {
            uint4 u = qp[i];
            const unsigned int w[4] = {u.x, u.y, u.z, u.w};
            #pragma unroll
            for (int j = 0; j < 4; ++j) {
                qreg[i * 8 + j * 2 + 0] = __uint_as_float(w[j] << 16) * 0.125f;
                qreg[i * 8 + j * 2 + 1] = __uint_as_float(w[j] & 0xffff0000u) * 0.125f;
            }
        }
    }
    float mrun = -1e30f, lrunv = 0.f;
    float oacc[4] = {0.f, 0.f, 0.f, 0.f};
    const int lr = tid >> 3, lc = (tid & 7) * 8;
    for (int kt = 0; kt < SEQ; kt += 64) {
        __syncthreads();
        #pragma unroll
        for (int half = 0; half < 2; ++half) {
            const int r = lr + half * 32;
            const size_t rowoff = (row0 + kt + r) * 2048 + h * 64 + lc;
            uint4 ku = *(const uint4*)(xu + rowoff);
            uint4 vu = *(const uint4*)(xu + rowoff + 1024);
            float4 f0, f1;
            f0.x = __uint_as_float(ku.x << 16); f0.y = __uint_as_float(ku.x & 0xffff0000u);
            f0.z = __uint_as_float(ku.y << 16); f0.w = __uint_as_float(ku.y & 0xffff0000u);
            f1.x = __uint_as_float(ku.z << 16); f1.y = __uint_as_float(ku.z & 0xffff0000u);
            f1.z = __uint_as_float(ku.w << 16); f1.w = __uint_as_float(ku.w & 0xffff0000u);
            *(float4*)&Ksh[r][lc]     = f0;
            *(float4*)&Ksh[r][lc + 4] = f1;
            f0.x = __uint_as_float(vu.x << 16); f0.y = __uint_as_float(vu.x & 0xffff0000u);
            f0.z = __uint_as_float(vu.y << 16); f0.w = __uint_as_float(vu.y & 0xffff0000u);
            f1.x = __uint_as_float(vu.z << 16); f1.y = __uint_as_float(vu.z & 0xffff0000u);
            f1.z = __uint_as_float(vu.w << 16); f1.w = __uint_as_float(vu.w & 0xffff0000u);
            *(float4*)&Vsh[r][lc]     = f0;
            *(float4*)&Vsh[r][lc + 4] = f1;
        }
        __syncthreads();
        float sc[4];
        #pragma unroll
        for (int u = 0; u < 4; ++u) {
            const int kk = tj + 16 * u;
            float s = 0.f;
            #pragma unroll
            for (int d = 0; d < 64; ++d) s = fmaf(qreg[d], Ksh[kk][d], s);
            sc[u] = s;
        }
        float tmax = fmaxf(fmaxf(sc[0], sc[1]), fmaxf(sc[2], sc[3]));
        #pragma unroll
        for (int off = 8; off >= 1; off >>= 1)
            tmax = fmaxf(tmax, __shfl_xor(tmax, off, 16));
        const float mnew = fmaxf(mrun, tmax);
        const float alpha = __expf(mrun - mnew);
        float psum = 0.f;
        #pragma unroll
        for (int u = 0; u < 4; ++u) {
            const float p = __expf(sc[u] - mnew);
            Psh[qi][tj + 16 * u] = p;
            psum += p;
        }
        #pragma unroll
        for (int off = 8; off >= 1; off >>= 1)
            psum += __shfl_xor(psum, off, 16);
        lrunv = lrunv * alpha + psum;
        mrun = mnew;
        oacc[0] *= alpha; oacc[1] *= alpha; oacc[2] *= alpha; oacc[3] *= alpha;
        __syncthreads();
        #pragma unroll 8
        for (int kk = 0; kk < 64; ++kk) {
            const float p = Psh[qi][kk];
            const float4 v4 = *(const float4*)&Vsh[kk][tj * 4];
            oacc[0] = fmaf(p, v4.x, oacc[0]); oacc[1] = fmaf(p, v4.y, oacc[1]);
            oacc[2] = fmaf(p, v4.z, oacc[2]); oacc[3] = fmaf(p, v4.w, oacc[3]);
        }
    }
    const float inv = 1.f / lrunv;
    ushort4 st;
    st.x = f2bf(oacc[0] * inv); st.y = f2bf(oacc[1] * inv);
    st.z = f2bf(oacc[2] * inv); st.w = f2bf(oacc[3] * inv);
    *(ushort4*)(outus + (row0 + s0 + qi) * 2048 + h * 64 + tj * 4) = st;
}

__global__ __launch_bounds__(256)
void out_final(const float* __restrict__ W, const float* __restrict__ bias,
               unsigned short* __restrict__ outus)
{
    float* outf = (float*)outus;
    __shared__ unsigned short Asb[16][1032];
    __shared__ float Bs[16][68];
    const int tid = threadIdx.x;
    const int m0 = blockIdx.x * 16;
    const int tx = tid & 15, ty = tid >> 4;
    #pragma unroll 4
    for (int i = 0; i < 16; ++i)
        *(ushort4*)&Asb[i][tid * 4] =
            *(const ushort4*)(outus + (size_t)(m0 + i) * 2048 + tid * 4);
    __syncthreads();
    for (int n0 = 0; n0 < 1024; n0 += 64) {
        float acc[4] = {0.f, 0.f, 0.f, 0.f};
        for (int k0 = 0; k0 < HID; k0 += 16) {
            *(float4*)&Bs[ty][tx * 4] =
                *(const float4*)(W + (size_t)(k0 + ty) * HID + n0 + tx * 4);
            __syncthreads();
            #pragma unroll
            for (int kk = 0; kk < 16; ++kk) {
                const float a = bf2f(Asb[ty][k0 + kk]);
                const float4 b4 = *(const float4*)&Bs[kk][tx * 4];
                acc[0] = fmaf(a, b4.x, acc[0]); acc[1] = fmaf(a, b4.y, acc[1]);
                acc[2] = fmaf(a, b4.z, acc[2]); acc[3] = fmaf(a, b4.w, acc[3]);
            }
            __syncthreads();
        }
        const int n = n0 + tx * 4;
        float4 st;
        st.x = acc[0] + bias[n + 0]; st.y = acc[1] + bias[n + 1];
        st.z = acc[2] + bias[n + 2]; st.w = acc[3] + bias[n + 3];
        *(float4*)(outf + (size_t)(m0 + ty) * HID + n) = st;
    }
}

// ===========================================================================
extern "C" void kernel_launch(void* const* d_in, const int* in_sizes, int n_in,
                              void* d_out, int out_size, void* d_ws, size_t ws_size,
                              hipStream_t stream) {
    const float* x     = (const float*)d_in[0];
    const float* W_qkv = (const float*)d_in[1];
    const float* b_qkv = (const float*)d_in[2];
    const float* W_out = (const float*)d_in[3];
    const float* b_out = (const float*)d_in[4];

    dim3 blk(256);

    if (ws_size >= (size_t)56 * 1024 * 1024) {
        // qk 32 MB | Vt 16 MB | Wqkv^T 6 MB | Wout^T 2 MB (in d_ws)
        // xb (bf16 x, 16 MB) lives in d_out as scratch until the final GEMM.
        unsigned short* qkbuf  = (unsigned short*)d_ws;
        unsigned short* vtbuf  = qkbuf + (size_t)MTOT * 2048;
        unsigned short* wqkv_t = vtbuf + (size_t)1024 * MTOT;
        unsigned short* wout_t = wqkv_t + (size_t)3072 * 1024;
        unsigned short* xb     = (unsigned short*)d_out;

        cvt_x<<<dim3(MTOT * HID / 1024), blk, 0, stream>>>(x, xb);
        transpose_cvt<<<dim3(3072 / 32, 1024 / 32), blk, 0, stream>>>(
            W_qkv, wqkv_t, 1024, 3072);
        transpose_cvt<<<dim3(1024 / 32, 1024 / 32), blk, 0, stream>>>(
            W_out, wout_t, 1024, 1024);
        // q,k GEMM (N=2048): q scaled, k plain, row-major into qkbuf
        gemm_mfma<false, true, false><<<dim3(2048 / 128, MTOT / 128), blk, 0, stream>>>(
            xb, wqkv_t, b_qkv, (void*)qkbuf, 1024, 2048, 1024);
        // V^T GEMM (swapped operands): Vt[dg][b*2048+s] with coalesced stores
        gemm_mfma<false, false, true><<<dim3(MTOT / 128, 1024 / 128), blk, 0, stream>>>(
            wqkv_t + (size_t)2048 * 1024, xb, b_qkv + 2048, (void*)vtbuf,
            1024, MTOT, 1024);
        // flash attention (8-wave blocks); attn overwrites q-slice of qkbuf
        attn_mfma<<<dim3(SEQ / 256, NH, BATCH), dim3(512), 0, stream>>>(qkbuf, vtbuf);
        // out-proj (fp32 out, overwrites the d_out scratch)
        gemm_mfma<true, false, false><<<dim3(1024 / 128, MTOT / 128), blk, 0, stream>>>(
            qkbuf, wout_t, b_out, d_out, 2048, 1024, 1024);
    } else {
        // verified round-4 fallback (zero workspace)
        unsigned short* outus = (unsigned short*)d_out;
        unsigned short* xu    = (unsigned short*)d_in[0];
        qproj<<<dim3(HID / 64, MTOT / 64), blk, 0, stream>>>(x, W_qkv, b_qkv, outus);
        kv_inplace<<<dim3(MTOT / 16), blk, 0, stream>>>(W_qkv, b_qkv, xu);
        attn_fwd<<<dim3(SEQ / 16, NH, BATCH), blk, 0, stream>>>(xu, outus);
        out_final<<<dim3(MTOT / 16), blk, 0, stream>>>(W_out, b_out, outus);
    }
}

// Round 7
// 290.108 us; speedup vs baseline: 3.4135x; 3.4135x over previous
//
#include <hip/hip_runtime.h>

// Problem constants: B=4, S=2048, HIDDEN=1024, NH=16, HD=64
#define SEQ    2048
#define BATCH  4
#define HID    1024
#define NH     16
#define MTOT   (BATCH * SEQ)   // 8192

typedef __attribute__((ext_vector_type(8)))  short          short8;   // 8 bf16 frag
typedef __attribute__((ext_vector_type(4)))  float          f32x4;
typedef __attribute__((ext_vector_type(16))) float          f32x16;   // 32x32 C/D
typedef __attribute__((ext_vector_type(8)))  unsigned short ushort8v;
typedef __attribute__((ext_vector_type(4)))  unsigned int   uint4v;

#define QSCL 0.125f   // 1/sqrt(64); __expf supplies the log2e internally

__device__ __forceinline__ float bf2f(unsigned short u) {
    return __uint_as_float(((unsigned int)u) << 16);
}
__device__ __forceinline__ unsigned short f2bf(float f) {
    unsigned int u = __float_as_uint(f);
    u += 0x7fffu + ((u >> 16) & 1u);   // RNE
    return (unsigned short)(u >> 16);
}
// pack two fp32 -> two bf16 (round-half-up) in one uint
__device__ __forceinline__ unsigned int pk2bf(float lo, float hi) {
    unsigned int ul = __float_as_uint(lo) + 0x8000u;
    unsigned int uh = __float_as_uint(hi) + 0x8000u;
    return __builtin_amdgcn_perm(uh, ul, 0x07060302u);
}

// async global->LDS, 16B per lane (global_load_lds_dwordx4)
__device__ __forceinline__ void gl_lds16(const void* g, void* l) {
    __builtin_amdgcn_global_load_lds(
        (__attribute__((address_space(1))) void*)g,
        (__attribute__((address_space(3))) void*)l, 16, 0, 0);
}

// XOR swizzle on 8-element (16B) groups for [*][64] tiles (8 slots/row)
__device__ __forceinline__ int swz64(int row, int col) {
    return row * 64 + ((((col >> 3) ^ (row & 7))) << 3) + (col & 7);
}

// GEMM BK=64 granule layout: granule (row,kq) of a [128][64] bf16 tile at
// ushort offset (row*8 + ((kq + (row&7)) & 7)) * 8.
__device__ __forceinline__ int gidx64(int row, int kq) {
    return (row * 8 + ((kq + (row & 7)) & 7)) * 8;
}

// ===========================================================================
// x fp32 -> bf16 (to d_out scratch). 4 elems/thread.
// ===========================================================================
__global__ __launch_bounds__(256)
void cvt_x(const float* __restrict__ x, unsigned short* __restrict__ xb)
{
    const size_t i = ((size_t)blockIdx.x * 256 + threadIdx.x) * 4;
    const float4 f = *(const float4*)(x + i);
    uint2 u;
    u.x = pk2bf(f.x, f.y);
    u.y = pk2bf(f.z, f.w);
    *(uint2*)(xb + i) = u;
}

// ===========================================================================
// Weight transpose + fp32->bf16: Wt[N][K] = bf16(W[K][N])
// ===========================================================================
__global__ __launch_bounds__(256)
void transpose_cvt(const float* __restrict__ W, unsigned short* __restrict__ Wt,
                   int K, int N)
{
    __shared__ unsigned short T[32][33];
    const int n0 = blockIdx.x * 32, k0 = blockIdx.y * 32;
    const int tr = threadIdx.x >> 3, tc = (threadIdx.x & 7) * 4;
    const float4 f = *(const float4*)(W + (size_t)(k0 + tr) * N + n0 + tc);
    T[tr][tc + 0] = f2bf(f.x);
    T[tr][tc + 1] = f2bf(f.y);
    T[tr][tc + 2] = f2bf(f.z);
    T[tr][tc + 3] = f2bf(f.w);
    __syncthreads();
    ushort4 u;
    u.x = T[tc + 0][tr]; u.y = T[tc + 1][tr];
    u.z = T[tc + 2][tr]; u.w = T[tc + 3][tr];
    *(ushort4*)(Wt + (size_t)(n0 + tr) * K + k0 + tc) = u;
}

// ===========================================================================
// MFMA GEMM, 128x128 tile, BK=64, async global_load_lds staging.
// A bf16 [M][lda]; B transposed bf16 Bt[N][K].
// VSPLIT (qk gemm, N=2048): cols [0,1024) q -> *QSCL bf16; rest k -> bf16.
// BIASROW (v gemm): bias indexed by ROW (C = Wv^T x^T), bf16 C.
// Else: fp32 (OUTF32) or bf16 C.
// ===========================================================================
template<bool OUTF32, bool VSPLIT, bool BIASROW>
__global__ __launch_bounds__(256)
void gemm_mfma(const unsigned short* __restrict__ A,
               const unsigned short* __restrict__ Bt,
               const float* __restrict__ bias, void* __restrict__ Cptr,
               int lda, int ldc, int K)
{
    __shared__ unsigned short As[128 * 64];   // 16 KB
    __shared__ unsigned short Bs[128 * 64];   // 16 KB

    const int tid = threadIdx.x;
    const int wave = tid >> 6, lane = tid & 63;
    const int quad = lane >> 4, lm = lane & 15;
    const int wm = wave & 1, wn = wave >> 1;
    const int m0 = blockIdx.y * 128, n0 = blockIdx.x * 128;

    // staging pointers: 4 granules per thread per matrix per K-step
    const unsigned short* aSrc[4];
    const unsigned short* bSrc[4];
    unsigned short* aDst[4];
    unsigned short* bDst[4];
    #pragma unroll
    for (int j = 0; j < 4; ++j) {
        const int g = (wave * 4 + j) * 64 + lane;   // granule 0..1023
        const int row = g >> 3;
        const int kq = ((g & 7) - (row & 7)) & 7;
        aSrc[j] = A  + (size_t)(m0 + row) * lda + kq * 8;
        bSrc[j] = Bt + (size_t)(n0 + row) * K   + kq * 8;
        aDst[j] = &As[g * 8];
        bDst[j] = &Bs[g * 8];
    }

    f32x4 acc[4][4];
    #pragma unroll
    for (int i = 0; i < 4; ++i)
        #pragma unroll
        for (int j = 0; j < 4; ++j)
            acc[i][j] = (f32x4){0.f, 0.f, 0.f, 0.f};

    // fragment LDS offsets (2 k-halves x 4 tiles), conflict-free
    int aOff[2][4], bOff[2][4];
    #pragma unroll
    for (int h = 0; h < 2; ++h)
        #pragma unroll
        for (int i = 0; i < 4; ++i) {
            aOff[h][i] = gidx64(wm * 64 + i * 16 + lm, h * 4 + quad);
            bOff[h][i] = gidx64(wn * 64 + i * 16 + lm, h * 4 + quad);
        }

    for (int k0 = 0; k0 < K; k0 += 64) {
        __syncthreads();                    // prev consumers done
        #pragma unroll
        for (int j = 0; j < 4; ++j) gl_lds16(aSrc[j] + k0, aDst[j]);
        #pragma unroll
        for (int j = 0; j < 4; ++j) gl_lds16(bSrc[j] + k0, bDst[j]);
        __syncthreads();                    // DMA visible

        #pragma unroll
        for (int h = 0; h < 2; ++h) {
            short8 af[4], bf[4];
            #pragma unroll
            for (int i = 0; i < 4; ++i) af[i] = *(const short8*)&As[aOff[h][i]];
            #pragma unroll
            for (int j = 0; j < 4; ++j) bf[j] = *(const short8*)&Bs[bOff[h][j]];
            #pragma unroll
            for (int i = 0; i < 4; ++i)
                #pragma unroll
                for (int j = 0; j < 4; ++j)
                    acc[i][j] = __builtin_amdgcn_mfma_f32_16x16x32_bf16(
                        af[i], bf[j], acc[i][j], 0, 0, 0);
        }
    }

    float bj[4];        // per-col bias (normal)
    float br[4][4];     // per-row bias (BIASROW): [i][rr]
    if constexpr (BIASROW) {
        #pragma unroll
        for (int i = 0; i < 4; ++i) {
            const float4 t =
                *(const float4*)(bias + m0 + wm * 64 + i * 16 + quad * 4);
            br[i][0] = t.x; br[i][1] = t.y; br[i][2] = t.z; br[i][3] = t.w;
        }
    } else {
        #pragma unroll
        for (int j = 0; j < 4; ++j) bj[j] = bias[n0 + wn * 64 + j * 16 + lm];
    }

    #pragma unroll
    for (int i = 0; i < 4; ++i) {
        #pragma unroll
        for (int j = 0; j < 4; ++j) {
            const int col = n0 + wn * 64 + j * 16 + lm;
            #pragma unroll
            for (int rr = 0; rr < 4; ++rr) {
                const int row = m0 + wm * 64 + i * 16 + quad * 4 + rr;
                float v = acc[i][j][rr] + (BIASROW ? br[i][rr] : bj[j]);
                if constexpr (VSPLIT) {
                    if (col < 1024) v *= QSCL;   // q pre-scale
                    ((unsigned short*)Cptr)[(size_t)row * ldc + col] = f2bf(v);
                } else if constexpr (OUTF32) {
                    ((float*)Cptr)[(size_t)row * ldc + col] = v;
                } else {
                    ((unsigned short*)Cptr)[(size_t)row * ldc + col] = f2bf(v);
                }
            }
        }
    }
}

// ===========================================================================
// MFMA flash attention v8b: 8-wave (512-thread) blocks = 4 q-waves x 2
// kv-halves; identical to v8 except the launch bound.
// v8 FAILURE ANALYSIS: __launch_bounds__(512,4) -> hipcc applied CUDA
// blocks/CU semantics: 4 blocks x 8 waves / 4 SIMDs = 8 waves/SIMD ->
// VGPR cap 64 -> total spill (WRITE_SIZE 2.12 GB, attn 803 us, VGPR=64
// in rocprof). (512,2) gives >=128 VGPRs under EITHER interpretation
// (2 blk/CU -> 4 w/SIMD -> 128; or 2 w/EU -> 256); kernel needs ~112.
// LDS (66 KB) caps residency at 2 blocks/CU regardless.
// ===========================================================================
__global__ __launch_bounds__(512, 2)
void attn_mfma(unsigned short* __restrict__ qk,
               const unsigned short* __restrict__ Vt)
{
    const int qt = blockIdx.x, hh = blockIdx.y, b = blockIdx.z;
    const size_t row0 = (size_t)b * SEQ;
    const int tid = threadIdx.x;
    const int wave = tid >> 6, lane = tid & 63;
    const int wq = wave & 3;          // q-tile within block
    const int kh = wave >> 2;         // kv half (0: kt 0..1023, 1: 1024..2047)
    const int l5 = lane >> 5, lm = lane & 31;

    __shared__ union {
        struct {
            unsigned short Ks[2][2][64 * 64];   // [buf][half][kvpos][d] swz64
            unsigned short Vs[2][2][64 * 64];   // [buf][half][d][kvpos] swz64
        } t;                                    // 64 KB
        float Ocmb[4][64][64];                  // [wq][frag][lane] f32 partials
    } u;
    __shared__ float Lcmb[4][2][64];            // [wq][qg][lane]

    const int qbase = qt * 256 + wq * 64;

    short8 qf[2][4];
    #pragma unroll
    for (int qg = 0; qg < 2; ++qg)
        #pragma unroll
        for (int ks = 0; ks < 4; ++ks)
            qf[qg][ks] = *(const short8*)(
                qk + (row0 + qbase + qg * 32 + lm) * 2048 + hh * 64 + ks * 16 + l5 * 8);

    f32x16 oacc[2][2];
    #pragma unroll
    for (int dg = 0; dg < 2; ++dg)
        #pragma unroll
        for (int qg = 0; qg < 2; ++qg)
            #pragma unroll
            for (int e = 0; e < 16; ++e) oacc[dg][qg][e] = 0.f;
    float lrun[2] = {0.f, 0.f};

    // DMA staging: per step stage 4 matrices (K,V for both halves), 512
    // granules each; thread (wave,lane) owns granule g = wave*64+lane of
    // every matrix. row=g>>3, slot=g&7, src col-group = slot^(row&7)
    // (inverse of the swz64 read involution; LDS dest is linear).
    const int g    = wave * 64 + lane;
    const int grow = g >> 3, gslot = g & 7;
    const int colg = gslot ^ (grow & 7);
    const int dOff = g * 8;
    // K source for half h: kv row = h*1024 + step*64 + grow
    const unsigned short* kSrcH[2];
    const unsigned short* vSrcH[2];
    #pragma unroll
    for (int h = 0; h < 2; ++h) {
        kSrcH[h] = qk + 1024 + hh * 64 + (row0 + h * 1024 + grow) * 2048 + colg * 8;
        vSrcH[h] = Vt + (size_t)(hh * 64 + grow) * (size_t)MTOT
                      + (size_t)b * SEQ + h * 1024 + colg * 8;
    }

    // prologue: stage step 0 into buffer 0
    #pragma unroll
    for (int h = 0; h < 2; ++h) {
        gl_lds16(kSrcH[h], &u.t.Ks[0][h][dOff]);
        gl_lds16(vSrcH[h], &u.t.Vs[0][h][dOff]);
    }
    __syncthreads();   // drains DMA before first reads

    int cur = 0;
    for (int st = 0; st < 16; ++st) {
        if (st + 1 < 16) {   // issue next step's DMA into the other buffer
            const size_t ko = (size_t)((st + 1) * 64) * 2048;
            const int vo = (st + 1) * 64;
            #pragma unroll
            for (int h = 0; h < 2; ++h) {
                gl_lds16(kSrcH[h] + ko, &u.t.Ks[cur ^ 1][h][dOff]);
                gl_lds16(vSrcH[h] + vo, &u.t.Vs[cur ^ 1][h][dOff]);
            }
        }
        const unsigned short* ksc = u.t.Ks[cur][kh];
        const unsigned short* vsc = u.t.Vs[cur][kh];

        #pragma unroll
        for (int kg = 0; kg < 2; ++kg) {
            short8 aK[4];
            #pragma unroll
            for (int ks = 0; ks < 4; ++ks)
                aK[ks] = *(const short8*)&ksc[swz64(kg * 32 + lm, ks * 16 + l5 * 8)];

            // QK^T (swapped: rows = k, cols = q) then exp, all in-register.
            f32x16 s[2];
            #pragma unroll
            for (int qg = 0; qg < 2; ++qg) {
                #pragma unroll
                for (int e = 0; e < 16; ++e) s[qg][e] = 0.f;
                __builtin_amdgcn_s_setprio(1);
                #pragma unroll
                for (int ks = 0; ks < 4; ++ks)
                    s[qg] = __builtin_amdgcn_mfma_f32_32x32x16_bf16(
                        aK[ks], qf[qg][ks], s[qg], 0, 0, 0);
                __builtin_amdgcn_s_setprio(0);
                float ls = 0.f;
                #pragma unroll
                for (int rg = 0; rg < 4; ++rg) {
                    const float p0 = __expf(s[qg][rg * 4 + 0]);
                    const float p1 = __expf(s[qg][rg * 4 + 1]);
                    const float p2 = __expf(s[qg][rg * 4 + 2]);
                    const float p3 = __expf(s[qg][rg * 4 + 3]);
                    s[qg][rg * 4 + 0] = p0; s[qg][rg * 4 + 1] = p1;
                    s[qg][rg * 4 + 2] = p2; s[qg][rg * 4 + 3] = p3;
                    ls += (p0 + p1) + (p2 + p3);
                }
                lrun[qg] += ls;
            }

            // PV: build B-fragment in-register (T12).
            // s[qg] reg r holds P[row = kg*32 + (r&3)+8*(r>>2)+4*l5][q=lm].
            #pragma unroll
            for (int step = 0; step < 2; ++step) {
                const int ks = kg * 2 + step;
                const short8 aV0 =
                    *(const short8*)&vsc[swz64(lm,      ks * 16 + l5 * 8)];
                const short8 aV1 =
                    *(const short8*)&vsc[swz64(32 + lm, ks * 16 + l5 * 8)];
                #pragma unroll
                for (int qg = 0; qg < 2; ++qg) {
                    const int b0 = step * 8;
                    const unsigned int uu = pk2bf(s[qg][b0 + 0], s[qg][b0 + 1]);
                    const unsigned int vv = pk2bf(s[qg][b0 + 2], s[qg][b0 + 3]);
                    const unsigned int u2 = pk2bf(s[qg][b0 + 4], s[qg][b0 + 5]);
                    const unsigned int v2 = pk2bf(s[qg][b0 + 6], s[qg][b0 + 7]);
                    const auto rA =
                        __builtin_amdgcn_permlane32_swap(uu, u2, false, false);
                    const auto rB =
                        __builtin_amdgcn_permlane32_swap(vv, v2, false, false);
                    uint4v wv;
                    wv.x = rA[0]; wv.y = rB[0]; wv.z = rA[1]; wv.w = rB[1];
                    const short8 bP = __builtin_bit_cast(short8, wv);
                    __builtin_amdgcn_s_setprio(1);
                    oacc[0][qg] = __builtin_amdgcn_mfma_f32_32x32x16_bf16(
                        aV0, bP, oacc[0][qg], 0, 0, 0);
                    oacc[1][qg] = __builtin_amdgcn_mfma_f32_32x32x16_bf16(
                        aV1, bP, oacc[1][qg], 0, 0, 0);
                    __builtin_amdgcn_s_setprio(0);
                }
            }
        }
        __syncthreads();   // readers of cur done; next-step DMA drained
        cur ^= 1;
    }

    // ---- combine halves through LDS (K/V buffers are dead past the last
    //      barrier; no DMA in flight for step 16) ----
    if (kh == 1) {
        #pragma unroll
        for (int dg = 0; dg < 2; ++dg)
            #pragma unroll
            for (int qg = 0; qg < 2; ++qg)
                #pragma unroll
                for (int e = 0; e < 16; ++e)
                    u.Ocmb[wq][(dg * 2 + qg) * 16 + e][lane] = oacc[dg][qg][e];
        Lcmb[wq][0][lane] = lrun[0];
        Lcmb[wq][1][lane] = lrun[1];
    }
    __syncthreads();
    if (kh == 0) {
        #pragma unroll
        for (int dg = 0; dg < 2; ++dg)
            #pragma unroll
            for (int qg = 0; qg < 2; ++qg)
                #pragma unroll
                for (int e = 0; e < 16; ++e)
                    oacc[dg][qg][e] += u.Ocmb[wq][(dg * 2 + qg) * 16 + e][lane];
        lrun[0] += Lcmb[wq][0][lane];
        lrun[1] += Lcmb[wq][1][lane];

        float linv[2];
        #pragma unroll
        for (int qg = 0; qg < 2; ++qg) {
            const float lt = lrun[qg] + __shfl_xor(lrun[qg], 32);
            linv[qg] = 1.f / lt;
        }

        #pragma unroll
        for (int dg = 0; dg < 2; ++dg)
            #pragma unroll
            for (int qg = 0; qg < 2; ++qg) {
                unsigned short* orow =
                    qk + (row0 + qbase + qg * 32 + lm) * 2048 + hh * 64;
                #pragma unroll
                for (int rg = 0; rg < 4; ++rg) {
                    const int d0 = dg * 32 + rg * 8 + l5 * 4;
                    ushort4 st;
                    st.x = f2bf(oacc[dg][qg][rg * 4 + 0] * linv[qg]);
                    st.y = f2bf(oacc[dg][qg][rg * 4 + 1] * linv[qg]);
                    st.z = f2bf(oacc[dg][qg][rg * 4 + 2] * linv[qg]);
                    st.w = f2bf(oacc[dg][qg][rg * 4 + 3] * linv[qg]);
                    *(ushort4*)(orow + d0) = st;
                }
            }
    }
}

// ===========================================================================
// ================= FALLBACK PATH (round-4, verified PASS) ==================
// ===========================================================================
__global__ __launch_bounds__(256)
void qproj(const float* __restrict__ A, const float* __restrict__ W,
           const float* __restrict__ bias, unsigned short* __restrict__ outus)
{
    __shared__ float As[64][17];
    __shared__ float Bs[16][64];
    const int tid = threadIdx.x;
    const int tx = tid & 15, ty = tid >> 4;
    const int m0 = blockIdx.y * 64, n0 = blockIdx.x * 64;
    const int ar = tid >> 2, ac = (tid & 3) * 4;
    const int br = tid >> 4, bc = (tid & 15) * 4;
    float acc[4][4] = {{0.f}};
    for (int k0 = 0; k0 < HID; k0 += 16) {
        const float4 av = *(const float4*)(A + (size_t)(m0 + ar) * HID + k0 + ac);
        As[ar][ac + 0] = av.x; As[ar][ac + 1] = av.y;
        As[ar][ac + 2] = av.z; As[ar][ac + 3] = av.w;
        *(float4*)&Bs[br][bc] =
            *(const float4*)(W + (size_t)(k0 + br) * 3072 + n0 + bc);
        __syncthreads();
        #pragma unroll
        for (int kk = 0; kk < 16; ++kk) {
            float a[4];
            #pragma unroll
            for (int i = 0; i < 4; ++i) a[i] = As[ty * 4 + i][kk];
            const float4 b4 = *(const float4*)&Bs[kk][tx * 4];
            const float bv[4] = {b4.x, b4.y, b4.z, b4.w};
            #pragma unroll
            for (int i = 0; i < 4; ++i)
                #pragma unroll
                for (int j = 0; j < 4; ++j)
                    acc[i][j] = fmaf(a[i], bv[j], acc[i][j]);
        }
        __syncthreads();
    }
    float bb[4];
    #pragma unroll
    for (int j = 0; j < 4; ++j) bb[j] = bias[n0 + tx * 4 + j];
    #pragma unroll
    for (int i = 0; i < 4; ++i) {
        ushort4 st;
        st.x = f2bf(acc[i][0] + bb[0]); st.y = f2bf(acc[i][1] + bb[1]);
        st.z = f2bf(acc[i][2] + bb[2]); st.w = f2bf(acc[i][3] + bb[3]);
        *(ushort4*)(outus + (size_t)(m0 + ty * 4 + i) * 2048 + 1024 + n0 + tx * 4) = st;
    }
}

__global__ __launch_bounds__(256)
void kv_inplace(const float* __restrict__ W, const float* __restrict__ bias,
                unsigned short* __restrict__ xu)
{
    const float* xf = (const float*)xu;
    __shared__ unsigned short Asb[16][1032];
    __shared__ float Bs[16][68];
    const int tid = threadIdx.x;
    const int m0 = blockIdx.x * 16;
    const int tx = tid & 15, ty = tid >> 4;
    #pragma unroll 4
    for (int i = 0; i < 16; ++i) {
        const float4 v = *(const float4*)(xf + (size_t)(m0 + i) * HID + tid * 4);
        ushort4 s;
        s.x = f2bf(v.x); s.y = f2bf(v.y); s.z = f2bf(v.z); s.w = f2bf(v.w);
        *(ushort4*)&Asb[i][tid * 4] = s;
    }
    __syncthreads();
    for (int n0 = 0; n0 < 2048; n0 += 64) {
        float acc[4] = {0.f, 0.f, 0.f, 0.f};
        for (int k0 = 0; k0 < HID; k0 += 16) {
            *(float4*)&Bs[ty][tx * 4] =
                *(const float4*)(W + (size_t)(k0 + ty) * 3072 + 1024 + n0 + tx * 4);
            __syncthreads();
            #pragma unroll
            for (int kk = 0; kk < 16; ++kk) {
                const float a = bf2f(Asb[ty][k0 + kk]);
                const float4 b4 = *(const float4*)&Bs[kk][tx * 4];
                acc[0] = fmaf(a, b4.x, acc[0]); acc[1] = fmaf(a, b4.y, acc[1]);
                acc[2] = fmaf(a, b4.z, acc[2]); acc[3] = fmaf(a, b4.w, acc[3]);
            }
            __syncthreads();
        }
        const int n = n0 + tx * 4;
        ushort4 s;
        s.x = f2bf(acc[0] + bias[1024 + n + 0]);
        s.y = f2bf(acc[1] + bias[1024 + n + 1]);
        s.z = f2bf(acc[2] + bias[1024 + n + 2]);
        s.w = f2bf(acc[3] + bias[1024 + n + 3]);
        *(ushort4*)(xu + (size_t)(m0 + ty) * 2048 + n) = s;
    }
}

__global__ __launch_bounds__(256)
void attn_fwd(const unsigned short* __restrict__ xu,
              unsigned short* __restrict__ outus)
{
    const int qt = blockIdx.x, h = blockIdx.y, b = blockIdx.z;
    const int s0 = qt * 16;
    const size_t row0 = (size_t)b * SEQ;
    const int tid = threadIdx.x;
    const int qi = tid >> 4, tj = tid & 15;
    __shared__ float Ksh[64][68];
    __shared__ float Vsh[64][68];
    __shared__ float Psh[16][68];
    float qreg[64];
    {
        const uint4* qp =
            (const uint4*)(outus + (row0 + s0 + qi) * 2048 + 1024 + h * 64);
        #pragma unroll
        for (int i = 0; i < 8; ++i) {
            uint4 u = qp[i];
            const unsigned int w[4] = {u.x, u.y, u.z, u.w};
            #pragma unroll
            for (int j = 0; j < 4; ++j) {
                qreg[i * 8 + j * 2 + 0] = __uint_as_float(w[j] << 16) * 0.125f;
                qreg[i * 8 + j * 2 + 1] = __uint_as_float(w[j] & 0xffff0000u) * 0.125f;
            }
        }
    }
    float mrun = -1e30f, lrunv = 0.f;
    float oacc[4] = {0.f, 0.f, 0.f, 0.f};
    const int lr = tid >> 3, lc = (tid & 7) * 8;
    for (int kt = 0; kt < SEQ; kt += 64) {
        __syncthreads();
        #pragma unroll
        for (int half = 0; half < 2; ++half) {
            const int r = lr + half * 32;
            const size_t rowoff = (row0 + kt + r) * 2048 + h * 64 + lc;
            uint4 ku = *(const uint4*)(xu + rowoff);
            uint4 vu = *(const uint4*)(xu + rowoff + 1024);
            float4 f0, f1;
            f0.x = __uint_as_float(ku.x << 16); f0.y = __uint_as_float(ku.x & 0xffff0000u);
            f0.z = __uint_as_float(ku.y << 16); f0.w = __uint_as_float(ku.y & 0xffff0000u);
            f1.x = __uint_as_float(ku.z << 16); f1.y = __uint_as_float(ku.z & 0xffff0000u);
            f1.z = __uint_as_float(ku.w << 16); f1.w = __uint_as_float(ku.w & 0xffff0000u);
            *(float4*)&Ksh[r][lc]     = f0;
            *(float4*)&Ksh[r][lc + 4] = f1;
            f0.x = __uint_as_float(vu.x << 16); f0.y = __uint_as_float(vu.x & 0xffff0000u);
            f0.z = __uint_as_float(vu.y << 16); f0.w = __uint_as_float(vu.y & 0xffff0000u);
            f1.x = __uint_as_float(vu.z << 16); f1.y = __uint_as_float(vu.z & 0xffff0000u);
            f1.z = __uint_as_float(vu.w << 16); f1.w = __uint_as_float(vu.w & 0xffff0000u);
            *(float4*)&Vsh[r][lc]     = f0;
            *(float4*)&Vsh[r][lc + 4] = f1;
        }
        __syncthreads();
        float sc[4];
        #pragma unroll
        for (int u = 0; u < 4; ++u) {
            const int kk = tj + 16 * u;
            float s = 0.f;
            #pragma unroll
            for (int d = 0; d < 64; ++d) s = fmaf(qreg[d], Ksh[kk][d], s);
            sc[u] = s;
        }
        float tmax = fmaxf(fmaxf(sc[0], sc[1]), fmaxf(sc[2], sc[3]));
        #pragma unroll
        for (int off = 8; off >= 1; off >>= 1)
            tmax = fmaxf(tmax, __shfl_xor(tmax, off, 16));
        const float mnew = fmaxf(mrun, tmax);
        const float alpha = __expf(mrun - mnew);
        float psum = 0.f;
        #pragma unroll
        for (int u = 0; u < 4; ++u) {
            const float p = __expf(sc[u] - mnew);
            Psh[qi][tj + 16 * u] = p;
            psum += p;
        }
        #pragma unroll
        for (int off = 8; off >= 1; off >>= 1)
            psum += __shfl_xor(psum, off, 16);
        lrunv = lrunv * alpha + psum;
        mrun = mnew;
        oacc[0] *= alpha; oacc[1] *= alpha; oacc[2] *= alpha; oacc[3] *= alpha;
        __syncthreads();
        #pragma unroll 8
        for (int kk = 0; kk < 64; ++kk) {
            const float p = Psh[qi][kk];
            const float4 v4 = *(const float4*)&Vsh[kk][tj * 4];
            oacc[0] = fmaf(p, v4.x, oacc[0]); oacc[1] = fmaf(p, v4.y, oacc[1]);
            oacc[2] = fmaf(p, v4.z, oacc[2]); oacc[3] = fmaf(p, v4.w, oacc[3]);
        }
    }
    const float inv = 1.f / lrunv;
    ushort4 st;
    st.x = f2bf(oacc[0] * inv); st.y = f2bf(oacc[1] * inv);
    st.z = f2bf(oacc[2] * inv); st.w = f2bf(oacc[3] * inv);
    *(ushort4*)(outus + (row0 + s0 + qi) * 2048 + h * 64 + tj * 4) = st;
}

__global__ __launch_bounds__(256)
void out_final(const float* __restrict__ W, const float* __restrict__ bias,
               unsigned short* __restrict__ outus)
{
    float* outf = (float*)outus;
    __shared__ unsigned short Asb[16][1032];
    __shared__ float Bs[16][68];
    const int tid = threadIdx.x;
    const int m0 = blockIdx.x * 16;
    const int tx = tid & 15, ty = tid >> 4;
    #pragma unroll 4
    for (int i = 0; i < 16; ++i)
        *(ushort4*)&Asb[i][tid * 4] =
            *(const ushort4*)(outus + (size_t)(m0 + i) * 2048 + tid * 4);
    __syncthreads();
    for (int n0 = 0; n0 < 1024; n0 += 64) {
        float acc[4] = {0.f, 0.f, 0.f, 0.f};
        for (int k0 = 0; k0 < HID; k0 += 16) {
            *(float4*)&Bs[ty][tx * 4] =
                *(const float4*)(W + (size_t)(k0 + ty) * HID + n0 + tx * 4);
            __syncthreads();
            #pragma unroll
            for (int kk = 0; kk < 16; ++kk) {
                const float a = bf2f(Asb[ty][k0 + kk]);
                const float4 b4 = *(const float4*)&Bs[kk][tx * 4];
                acc[0] = fmaf(a, b4.x, acc[0]); acc[1] = fmaf(a, b4.y, acc[1]);
                acc[2] = fmaf(a, b4.z, acc[2]); acc[3] = fmaf(a, b4.w, acc[3]);
            }
            __syncthreads();
        }
        const int n = n0 + tx * 4;
        float4 st;
        st.x = acc[0] + bias[n + 0]; st.y = acc[1] + bias[n + 1];
        st.z = acc[2] + bias[n + 2]; st.w = acc[3] + bias[n + 3];
        *(float4*)(outf + (size_t)(m0 + ty) * HID + n) = st;
    }
}

// ===========================================================================
extern "C" void kernel_launch(void* const* d_in, const int* in_sizes, int n_in,
                              void* d_out, int out_size, void* d_ws, size_t ws_size,
                              hipStream_t stream) {
    const float* x     = (const float*)d_in[0];
    const float* W_qkv = (const float*)d_in[1];
    const float* b_qkv = (const float*)d_in[2];
    const float* W_out = (const float*)d_in[3];
    const float* b_out = (const float*)d_in[4];

    dim3 blk(256);

    if (ws_size >= (size_t)56 * 1024 * 1024) {
        // qk 32 MB | Vt 16 MB | Wqkv^T 6 MB | Wout^T 2 MB (in d_ws)
        // xb (bf16 x, 16 MB) lives in d_out as scratch until the final GEMM.
        unsigned short* qkbuf  = (unsigned short*)d_ws;
        unsigned short* vtbuf  = qkbuf + (size_t)MTOT * 2048;
        unsigned short* wqkv_t = vtbuf + (size_t)1024 * MTOT;
        unsigned short* wout_t = wqkv_t + (size_t)3072 * 1024;
        unsigned short* xb     = (unsigned short*)d_out;

        cvt_x<<<dim3(MTOT * HID / 1024), blk, 0, stream>>>(x, xb);
        transpose_cvt<<<dim3(3072 / 32, 1024 / 32), blk, 0, stream>>>(
            W_qkv, wqkv_t, 1024, 3072);
        transpose_cvt<<<dim3(1024 / 32, 1024 / 32), blk, 0, stream>>>(
            W_out, wout_t, 1024, 1024);
        // q,k GEMM (N=2048): q scaled, k plain, row-major into qkbuf
        gemm_mfma<false, true, false><<<dim3(2048 / 128, MTOT / 128), blk, 0, stream>>>(
            xb, wqkv_t, b_qkv, (void*)qkbuf, 1024, 2048, 1024);
        // V^T GEMM (swapped operands): Vt[dg][b*2048+s] with coalesced stores
        gemm_mfma<false, false, true><<<dim3(MTOT / 128, 1024 / 128), blk, 0, stream>>>(
            wqkv_t + (size_t)2048 * 1024, xb, b_qkv + 2048, (void*)vtbuf,
            1024, MTOT, 1024);
        // flash attention (8-wave blocks); attn overwrites q-slice of qkbuf
        attn_mfma<<<dim3(SEQ / 256, NH, BATCH), dim3(512), 0, stream>>>(qkbuf, vtbuf);
        // out-proj (fp32 out, overwrites the d_out scratch)
        gemm_mfma<true, false, false><<<dim3(1024 / 128, MTOT / 128), blk, 0, stream>>>(
            qkbuf, wout_t, b_out, d_out, 2048, 1024, 1024);
    } else {
        // verified round-4 fallback (zero workspace)
        unsigned short* outus = (unsigned short*)d_out;
        unsigned short* xu    = (unsigned short*)d_in[0];
        qproj<<<dim3(HID / 64, MTOT / 64), blk, 0, stream>>>(x, W_qkv, b_qkv, outus);
        kv_inplace<<<dim3(MTOT / 16), blk, 0, stream>>>(W_qkv, b_qkv, xu);
        attn_fwd<<<dim3(SEQ / 16, NH, BATCH), blk, 0, stream>>>(xu, outus);
        out_final<<<dim3(MTOT / 16), blk, 0, stream>>>(W_out, b_out, outus);
    }
}

// Round 8
// 276.342 us; speedup vs baseline: 3.5836x; 1.0498x over previous
//
#include <hip/hip_runtime.h>

// Problem constants: B=4, S=2048, HIDDEN=1024, NH=16, HD=64
#define SEQ    2048
#define BATCH  4
#define HID    1024
#define NH     16
#define MTOT   (BATCH * SEQ)   // 8192

typedef __attribute__((ext_vector_type(8)))  short          short8;   // 8 bf16 frag
typedef __attribute__((ext_vector_type(4)))  float          f32x4;
typedef __attribute__((ext_vector_type(16))) float          f32x16;   // 32x32 C/D
typedef __attribute__((ext_vector_type(8)))  unsigned short ushort8v;
typedef __attribute__((ext_vector_type(4)))  unsigned int   uint4v;

#define QSCL 0.125f   // 1/sqrt(64); __expf supplies the log2e internally

__device__ __forceinline__ float bf2f(unsigned short u) {
    return __uint_as_float(((unsigned int)u) << 16);
}
__device__ __forceinline__ unsigned short f2bf(float f) {
    unsigned int u = __float_as_uint(f);
    u += 0x7fffu + ((u >> 16) & 1u);   // RNE
    return (unsigned short)(u >> 16);
}
// pack two fp32 -> two bf16 (round-half-up) in one uint
__device__ __forceinline__ unsigned int pk2bf(float lo, float hi) {
    unsigned int ul = __float_as_uint(lo) + 0x8000u;
    unsigned int uh = __float_as_uint(hi) + 0x8000u;
    return __builtin_amdgcn_perm(uh, ul, 0x07060302u);
}

// async global->LDS, 16B per lane (global_load_lds_dwordx4)
__device__ __forceinline__ void gl_lds16(const void* g, void* l) {
    __builtin_amdgcn_global_load_lds(
        (__attribute__((address_space(1))) void*)g,
        (__attribute__((address_space(3))) void*)l, 16, 0, 0);
}

// XOR swizzle on 8-element (16B) groups for [*][64] tiles (8 slots/row)
__device__ __forceinline__ int swz64(int row, int col) {
    return row * 64 + ((((col >> 3) ^ (row & 7))) << 3) + (col & 7);
}

// GEMM BK=64 granule layout: granule (row,kq) of a [128][64] bf16 tile at
// ushort offset (row*8 + ((kq + (row&7)) & 7)) * 8.
__device__ __forceinline__ int gidx64(int row, int kq) {
    return (row * 8 + ((kq + (row & 7)) & 7)) * 8;
}

// ===========================================================================
// x fp32 -> bf16 (to d_out scratch). 4 elems/thread.
// ===========================================================================
__global__ __launch_bounds__(256)
void cvt_x(const float* __restrict__ x, unsigned short* __restrict__ xb)
{
    const size_t i = ((size_t)blockIdx.x * 256 + threadIdx.x) * 4;
    const float4 f = *(const float4*)(x + i);
    uint2 u;
    u.x = pk2bf(f.x, f.y);
    u.y = pk2bf(f.z, f.w);
    *(uint2*)(xb + i) = u;
}

// ===========================================================================
// Weight transpose + fp32->bf16: Wt[N][K] = bf16(W[K][N])
// ===========================================================================
__global__ __launch_bounds__(256)
void transpose_cvt(const float* __restrict__ W, unsigned short* __restrict__ Wt,
                   int K, int N)
{
    __shared__ unsigned short T[32][33];
    const int n0 = blockIdx.x * 32, k0 = blockIdx.y * 32;
    const int tr = threadIdx.x >> 3, tc = (threadIdx.x & 7) * 4;
    const float4 f = *(const float4*)(W + (size_t)(k0 + tr) * N + n0 + tc);
    T[tr][tc + 0] = f2bf(f.x);
    T[tr][tc + 1] = f2bf(f.y);
    T[tr][tc + 2] = f2bf(f.z);
    T[tr][tc + 3] = f2bf(f.w);
    __syncthreads();
    ushort4 u;
    u.x = T[tc + 0][tr]; u.y = T[tc + 1][tr];
    u.z = T[tc + 2][tr]; u.w = T[tc + 3][tr];
    *(ushort4*)(Wt + (size_t)(n0 + tr) * K + k0 + tc) = u;
}

// ===========================================================================
// MFMA GEMM, 128x128 tile, BK=64, async global_load_lds staging.
// T1 XCD swizzle: linear bid -> swz = (bid%8)*(nwg/8) + bid/8 (bijective,
// nwg%8==0 for all three launches: 1024/512/512). Each XCD owns a
// contiguous work band -> A-panel re-reads hit its own L2 instead of HBM.
// A bf16 [M][lda]; B transposed bf16 Bt[N][K].
// VSPLIT (qk gemm, N=2048): cols [0,1024) q -> *QSCL bf16; rest k -> bf16.
// BIASROW (v gemm): bias indexed by ROW (C = Wv^T x^T), bf16 C.
// Else: fp32 (OUTF32) or bf16 C.
// ===========================================================================
template<bool OUTF32, bool VSPLIT, bool BIASROW>
__global__ __launch_bounds__(256)
void gemm_mfma(const unsigned short* __restrict__ A,
               const unsigned short* __restrict__ Bt,
               const float* __restrict__ bias, void* __restrict__ Cptr,
               int lda, int ldc, int K)
{
    __shared__ unsigned short As[128 * 64];   // 16 KB
    __shared__ unsigned short Bs[128 * 64];   // 16 KB

    const int tid = threadIdx.x;
    const int wave = tid >> 6, lane = tid & 63;
    const int quad = lane >> 4, lm = lane & 15;
    const int wm = wave & 1, wn = wave >> 1;

    // T1 XCD-aware remap (dispatch is x-fastest; XCD = linear bid % 8)
    const int nwg = gridDim.x * gridDim.y;
    const int bid = blockIdx.y * gridDim.x + blockIdx.x;
    const int swz = (bid & 7) * (nwg >> 3) + (bid >> 3);
    const int m0 = (swz / gridDim.x) * 128;
    const int n0 = (swz % gridDim.x) * 128;

    // staging pointers: 4 granules per thread per matrix per K-step
    const unsigned short* aSrc[4];
    const unsigned short* bSrc[4];
    unsigned short* aDst[4];
    unsigned short* bDst[4];
    #pragma unroll
    for (int j = 0; j < 4; ++j) {
        const int g = (wave * 4 + j) * 64 + lane;   // granule 0..1023
        const int row = g >> 3;
        const int kq = ((g & 7) - (row & 7)) & 7;
        aSrc[j] = A  + (size_t)(m0 + row) * lda + kq * 8;
        bSrc[j] = Bt + (size_t)(n0 + row) * K   + kq * 8;
        aDst[j] = &As[g * 8];
        bDst[j] = &Bs[g * 8];
    }

    f32x4 acc[4][4];
    #pragma unroll
    for (int i = 0; i < 4; ++i)
        #pragma unroll
        for (int j = 0; j < 4; ++j)
            acc[i][j] = (f32x4){0.f, 0.f, 0.f, 0.f};

    // fragment LDS offsets (2 k-halves x 4 tiles), conflict-free
    int aOff[2][4], bOff[2][4];
    #pragma unroll
    for (int h = 0; h < 2; ++h)
        #pragma unroll
        for (int i = 0; i < 4; ++i) {
            aOff[h][i] = gidx64(wm * 64 + i * 16 + lm, h * 4 + quad);
            bOff[h][i] = gidx64(wn * 64 + i * 16 + lm, h * 4 + quad);
        }

    for (int k0 = 0; k0 < K; k0 += 64) {
        __syncthreads();                    // prev consumers done
        #pragma unroll
        for (int j = 0; j < 4; ++j) gl_lds16(aSrc[j] + k0, aDst[j]);
        #pragma unroll
        for (int j = 0; j < 4; ++j) gl_lds16(bSrc[j] + k0, bDst[j]);
        __syncthreads();                    // DMA visible

        #pragma unroll
        for (int h = 0; h < 2; ++h) {
            short8 af[4], bf[4];
            #pragma unroll
            for (int i = 0; i < 4; ++i) af[i] = *(const short8*)&As[aOff[h][i]];
            #pragma unroll
            for (int j = 0; j < 4; ++j) bf[j] = *(const short8*)&Bs[bOff[h][j]];
            #pragma unroll
            for (int i = 0; i < 4; ++i)
                #pragma unroll
                for (int j = 0; j < 4; ++j)
                    acc[i][j] = __builtin_amdgcn_mfma_f32_16x16x32_bf16(
                        af[i], bf[j], acc[i][j], 0, 0, 0);
        }
    }

    float bj[4];        // per-col bias (normal)
    float br[4][4];     // per-row bias (BIASROW): [i][rr]
    if constexpr (BIASROW) {
        #pragma unroll
        for (int i = 0; i < 4; ++i) {
            const float4 t =
                *(const float4*)(bias + m0 + wm * 64 + i * 16 + quad * 4);
            br[i][0] = t.x; br[i][1] = t.y; br[i][2] = t.z; br[i][3] = t.w;
        }
    } else {
        #pragma unroll
        for (int j = 0; j < 4; ++j) bj[j] = bias[n0 + wn * 64 + j * 16 + lm];
    }

    #pragma unroll
    for (int i = 0; i < 4; ++i) {
        #pragma unroll
        for (int j = 0; j < 4; ++j) {
            const int col = n0 + wn * 64 + j * 16 + lm;
            #pragma unroll
            for (int rr = 0; rr < 4; ++rr) {
                const int row = m0 + wm * 64 + i * 16 + quad * 4 + rr;
                float v = acc[i][j][rr] + (BIASROW ? br[i][rr] : bj[j]);
                if constexpr (VSPLIT) {
                    if (col < 1024) v *= QSCL;   // q pre-scale
                    ((unsigned short*)Cptr)[(size_t)row * ldc + col] = f2bf(v);
                } else if constexpr (OUTF32) {
                    ((float*)Cptr)[(size_t)row * ldc + col] = v;
                } else {
                    ((unsigned short*)Cptr)[(size_t)row * ldc + col] = f2bf(v);
                }
            }
        }
    }
}

// ===========================================================================
// MFMA flash attention v9: v7's verified compute (KVBLK=64, in-register P
// via T12, gl_lds dbuf staging, 256 threads, 102 us PASS) + T1 XCD grouping:
// flat 512-block grid, bid -> g = bid&63 (h,b pair), qt = bid>>6.
// The 8 qt-sibling blocks sharing one (h,b)'s K/V satisfy bid == g (mod 8)
// -> same XCD (round-robin dispatch), co-resident, lockstep kt walk ->
// K/V fetched from HBM once per XCD, 7 siblings hit the 4 MB L2
// (8 slices x 512 KB = 4 MB). Kills the 8x K/V HBM re-read that FETCH_SIZE
// exposed (139 MB ~ Q 16 + 8x16 K/V). v8/v8b 8-wave experiment refuted
// the TLP theory (occupancy up, perf flat) and is reverted.
// ===========================================================================
__global__ __launch_bounds__(256, 2)
void attn_mfma(unsigned short* __restrict__ qk,
               const unsigned short* __restrict__ Vt)
{
    const int bid = blockIdx.x;
    const int qt = bid >> 6;          // q-tile (slow dim -> same-XCD siblings)
    const int g  = bid & 63;          // (h,b) group; XCD = g & 7
    const int hh = g & 15;
    const int b  = g >> 4;
    const size_t row0 = (size_t)b * SEQ;
    const int tid = threadIdx.x;
    const int wave = tid >> 6, lane = tid & 63;
    const int l5 = lane >> 5, lm = lane & 31;

    __shared__ unsigned short Ks[2][64 * 64];   // 2 x 8 KB, [kvpos][d] swz64
    __shared__ unsigned short Vs[2][64 * 64];   // 2 x 8 KB, [d][kvpos] swz64

    const int qbase = qt * 256 + wave * 64;

    short8 qf[2][4];
    #pragma unroll
    for (int qg = 0; qg < 2; ++qg)
        #pragma unroll
        for (int ks = 0; ks < 4; ++ks)
            qf[qg][ks] = *(const short8*)(
                qk + (row0 + qbase + qg * 32 + lm) * 2048 + hh * 64 + ks * 16 + l5 * 8);

    f32x16 oacc[2][2];
    #pragma unroll
    for (int dg = 0; dg < 2; ++dg)
        #pragma unroll
        for (int qg = 0; qg < 2; ++qg)
            #pragma unroll
            for (int e = 0; e < 16; ++e) oacc[dg][qg][e] = 0.f;
    float lrun[2] = {0.f, 0.f};

    // DMA staging: 512 granules per matrix per tile = 256 thr x 2 issues.
    // granule g: row=g>>3 (K: kvpos, V: d), slot=g&7, src col-group=slot^(row&7).
    const unsigned short* kSrc[2];
    const unsigned short* vSrc[2];
    int dOff[2];
    #pragma unroll
    for (int jj = 0; jj < 2; ++jj) {
        const int gg = (wave * 2 + jj) * 64 + lane;
        const int row = gg >> 3, slot = gg & 7;
        const int colg = slot ^ (row & 7);
        kSrc[jj] = qk + 1024 + hh * 64 + (row0 + row) * 2048 + colg * 8;
        vSrc[jj] = Vt + (size_t)(hh * 64 + row) * (size_t)MTOT
                      + (size_t)b * SEQ + colg * 8;
        dOff[jj] = gg * 8;
    }

    // prologue: stage tile 0 into buffer 0
    #pragma unroll
    for (int jj = 0; jj < 2; ++jj) {
        gl_lds16(kSrc[jj], &Ks[0][dOff[jj]]);
        gl_lds16(vSrc[jj], &Vs[0][dOff[jj]]);
    }
    __syncthreads();   // drains DMA (vmcnt 0) before first reads

    int cur = 0;
    for (int kt = 0; kt < SEQ; kt += 64) {
        if (kt + 64 < SEQ) {   // issue next tile's DMA into the other buffer
            const size_t ko = (size_t)(kt + 64) * 2048;
            const int vo = kt + 64;
            #pragma unroll
            for (int jj = 0; jj < 2; ++jj) {
                gl_lds16(kSrc[jj] + ko, &Ks[cur ^ 1][dOff[jj]]);
                gl_lds16(vSrc[jj] + vo, &Vs[cur ^ 1][dOff[jj]]);
            }
        }
        const unsigned short* ksc = Ks[cur];
        const unsigned short* vsc = Vs[cur];

        #pragma unroll
        for (int kg = 0; kg < 2; ++kg) {
            short8 aK[4];
            #pragma unroll
            for (int ks = 0; ks < 4; ++ks)
                aK[ks] = *(const short8*)&ksc[swz64(kg * 32 + lm, ks * 16 + l5 * 8)];

            // QK^T (swapped: rows = k, cols = q) then exp, all in-register.
            f32x16 s[2];
            #pragma unroll
            for (int qg = 0; qg < 2; ++qg) {
                #pragma unroll
                for (int e = 0; e < 16; ++e) s[qg][e] = 0.f;
                __builtin_amdgcn_s_setprio(1);
                #pragma unroll
                for (int ks = 0; ks < 4; ++ks)
                    s[qg] = __builtin_amdgcn_mfma_f32_32x32x16_bf16(
                        aK[ks], qf[qg][ks], s[qg], 0, 0, 0);
                __builtin_amdgcn_s_setprio(0);
                float ls = 0.f;
                #pragma unroll
                for (int rg = 0; rg < 4; ++rg) {
                    const float p0 = __expf(s[qg][rg * 4 + 0]);
                    const float p1 = __expf(s[qg][rg * 4 + 1]);
                    const float p2 = __expf(s[qg][rg * 4 + 2]);
                    const float p3 = __expf(s[qg][rg * 4 + 3]);
                    s[qg][rg * 4 + 0] = p0; s[qg][rg * 4 + 1] = p1;
                    s[qg][rg * 4 + 2] = p2; s[qg][rg * 4 + 3] = p3;
                    ls += (p0 + p1) + (p2 + p3);
                }
                lrun[qg] += ls;
            }

            // PV: build B-fragment in-register (T12).
            // s[qg] reg r holds P[row = kg*32 + (r&3)+8*(r>>2)+4*l5][q=lm].
            #pragma unroll
            for (int step = 0; step < 2; ++step) {
                const int ks = kg * 2 + step;
                const short8 aV0 =
                    *(const short8*)&vsc[swz64(lm,      ks * 16 + l5 * 8)];
                const short8 aV1 =
                    *(const short8*)&vsc[swz64(32 + lm, ks * 16 + l5 * 8)];
                #pragma unroll
                for (int qg = 0; qg < 2; ++qg) {
                    const int b0 = step * 8;
                    const unsigned int u  = pk2bf(s[qg][b0 + 0], s[qg][b0 + 1]);
                    const unsigned int vv = pk2bf(s[qg][b0 + 2], s[qg][b0 + 3]);
                    const unsigned int u2 = pk2bf(s[qg][b0 + 4], s[qg][b0 + 5]);
                    const unsigned int v2 = pk2bf(s[qg][b0 + 6], s[qg][b0 + 7]);
                    const auto rA =
                        __builtin_amdgcn_permlane32_swap(u,  u2, false, false);
                    const auto rB =
                        __builtin_amdgcn_permlane32_swap(vv, v2, false, false);
                    uint4v wv;
                    wv.x = rA[0]; wv.y = rB[0]; wv.z = rA[1]; wv.w = rB[1];
                    const short8 bP = __builtin_bit_cast(short8, wv);
                    __builtin_amdgcn_s_setprio(1);
                    oacc[0][qg] = __builtin_amdgcn_mfma_f32_32x32x16_bf16(
                        aV0, bP, oacc[0][qg], 0, 0, 0);
                    oacc[1][qg] = __builtin_amdgcn_mfma_f32_32x32x16_bf16(
                        aV1, bP, oacc[1][qg], 0, 0, 0);
                    __builtin_amdgcn_s_setprio(0);
                }
            }
        }
        __syncthreads();   // readers of cur done; next-tile DMA drained (vmcnt 0)
        cur ^= 1;
    }

    float linv[2];
    #pragma unroll
    for (int qg = 0; qg < 2; ++qg) {
        const float lt = lrun[qg] + __shfl_xor(lrun[qg], 32);
        linv[qg] = 1.f / lt;
    }

    #pragma unroll
    for (int dg = 0; dg < 2; ++dg)
        #pragma unroll
        for (int qg = 0; qg < 2; ++qg) {
            unsigned short* orow =
                qk + (row0 + qbase + qg * 32 + lm) * 2048 + hh * 64;
            #pragma unroll
            for (int rg = 0; rg < 4; ++rg) {
                const int d0 = dg * 32 + rg * 8 + l5 * 4;
                ushort4 st;
                st.x = f2bf(oacc[dg][qg][rg * 4 + 0] * linv[qg]);
                st.y = f2bf(oacc[dg][qg][rg * 4 + 1] * linv[qg]);
                st.z = f2bf(oacc[dg][qg][rg * 4 + 2] * linv[qg]);
                st.w = f2bf(oacc[dg][qg][rg * 4 + 3] * linv[qg]);
                *(ushort4*)(orow + d0) = st;
            }
        }
}

// ===========================================================================
// ================= FALLBACK PATH (round-4, verified PASS) ==================
// ===========================================================================
__global__ __launch_bounds__(256)
void qproj(const float* __restrict__ A, const float* __restrict__ W,
           const float* __restrict__ bias, unsigned short* __restrict__ outus)
{
    __shared__ float As[64][17];
    __shared__ float Bs[16][64];
    const int tid = threadIdx.x;
    const int tx = tid & 15, ty = tid >> 4;
    const int m0 = blockIdx.y * 64, n0 = blockIdx.x * 64;
    const int ar = tid >> 2, ac = (tid & 3) * 4;
    const int br = tid >> 4, bc = (tid & 15) * 4;
    float acc[4][4] = {{0.f}};
    for (int k0 = 0; k0 < HID; k0 += 16) {
        const float4 av = *(const float4*)(A + (size_t)(m0 + ar) * HID + k0 + ac);
        As[ar][ac + 0] = av.x; As[ar][ac + 1] = av.y;
        As[ar][ac + 2] = av.z; As[ar][ac + 3] = av.w;
        *(float4*)&Bs[br][bc] =
            *(const float4*)(W + (size_t)(k0 + br) * 3072 + n0 + bc);
        __syncthreads();
        #pragma unroll
        for (int kk = 0; kk < 16; ++kk) {
            float a[4];
            #pragma unroll
            for (int i = 0; i < 4; ++i) a[i] = As[ty * 4 + i][kk];
            const float4 b4 = *(const float4*)&Bs[kk][tx * 4];
            const float bv[4] = {b4.x, b4.y, b4.z, b4.w};
            #pragma unroll
            for (int i = 0; i < 4; ++i)
                #pragma unroll
                for (int j = 0; j < 4; ++j)
                    acc[i][j] = fmaf(a[i], bv[j], acc[i][j]);
        }
        __syncthreads();
    }
    float bb[4];
    #pragma unroll
    for (int j = 0; j < 4; ++j) bb[j] = bias[n0 + tx * 4 + j];
    #pragma unroll
    for (int i = 0; i < 4; ++i) {
        ushort4 st;
        st.x = f2bf(acc[i][0] + bb[0]); st.y = f2bf(acc[i][1] + bb[1]);
        st.z = f2bf(acc[i][2] + bb[2]); st.w = f2bf(acc[i][3] + bb[3]);
        *(ushort4*)(outus + (size_t)(m0 + ty * 4 + i) * 2048 + 1024 + n0 + tx * 4) = st;
    }
}

__global__ __launch_bounds__(256)
void kv_inplace(const float* __restrict__ W, const float* __restrict__ bias,
                unsigned short* __restrict__ xu)
{
    const float* xf = (const float*)xu;
    __shared__ unsigned short Asb[16][1032];
    __shared__ float Bs[16][68];
    const int tid = threadIdx.x;
    const int m0 = blockIdx.x * 16;
    const int tx = tid & 15, ty = tid >> 4;
    #pragma unroll 4
    for (int i = 0; i < 16; ++i) {
        const float4 v = *(const float4*)(xf + (size_t)(m0 + i) * HID + tid * 4);
        ushort4 s;
        s.x = f2bf(v.x); s.y = f2bf(v.y); s.z = f2bf(v.z); s.w = f2bf(v.w);
        *(ushort4*)&Asb[i][tid * 4] = s;
    }
    __syncthreads();
    for (int n0 = 0; n0 < 2048; n0 += 64) {
        float acc[4] = {0.f, 0.f, 0.f, 0.f};
        for (int k0 = 0; k0 < HID; k0 += 16) {
            *(float4*)&Bs[ty][tx * 4] =
                *(const float4*)(W + (size_t)(k0 + ty) * 3072 + 1024 + n0 + tx * 4);
            __syncthreads();
            #pragma unroll
            for (int kk = 0; kk < 16; ++kk) {
                const float a = bf2f(Asb[ty][k0 + kk]);
                const float4 b4 = *(const float4*)&Bs[kk][tx * 4];
                acc[0] = fmaf(a, b4.x, acc[0]); acc[1] = fmaf(a, b4.y, acc[1]);
                acc[2] = fmaf(a, b4.z, acc[2]); acc[3] = fmaf(a, b4.w, acc[3]);
            }
            __syncthreads();
        }
        const int n = n0 + tx * 4;
        ushort4 s;
        s.x = f2bf(acc[0] + bias[1024 + n + 0]);
        s.y = f2bf(acc[1] + bias[1024 + n + 1]);
        s.z = f2bf(acc[2] + bias[1024 + n + 2]);
        s.w = f2bf(acc[3] + bias[1024 + n + 3]);
        *(ushort4*)(xu + (size_t)(m0 + ty) * 2048 + n) = s;
    }
}

__global__ __launch_bounds__(256)
void attn_fwd(const unsigned short* __restrict__ xu,
              unsigned short* __restrict__ outus)
{
    const int qt = blockIdx.x, h = blockIdx.y, b = blockIdx.z;
    const int s0 = qt * 16;
    const size_t row0 = (size_t)b * SEQ;
    const int tid = threadIdx.x;
    const int qi = tid >> 4, tj = tid & 15;
    __shared__ float Ksh[64][68];
    __shared__ float Vsh[64][68];
    __shared__ float Psh[16][68];
    float qreg[64];
    {
        const uint4* qp =
            (const uint4*)(outus + (row0 + s0 + qi) * 2048 + 1024 + h * 64);
        #pragma unroll
        for (int i = 0; i < 8; ++i) {
            uint4 u = qp[i];
            const unsigned int w[4] = {u.x, u.y, u.z, u.w};
            #pragma unroll
            for (int j = 0; j < 4; ++j) {
                qreg[i * 8 + j * 2 + 0] = __uint_as_float(w[j] << 16) * 0.125f;
                qreg[i * 8 + j * 2 + 1] = __uint_as_float(w[j] & 0xffff0000u) * 0.125f;
            }
        }
    }
    float mrun = -1e30f, lrunv = 0.f;
    float oacc[4] = {0.f, 0.f, 0.f, 0.f};
    const int lr = tid >> 3, lc = (tid & 7) * 8;
    for (int kt = 0; kt < SEQ; kt += 64) {
        __syncthreads();
        #pragma unroll
        for (int half = 0; half < 2; ++half) {
            const int r = lr + half * 32;
            const size_t rowoff = (row0 + kt + r) * 2048 + h * 64 + lc;
            uint4 ku = *(const uint4*)(xu + rowoff);
            uint4 vu = *(const uint4*)(xu + rowoff + 1024);
            float4 f0, f1;
            f0.x = __uint_as_float(ku.x << 16); f0.y = __uint_as_float(ku.x & 0xffff0000u);
            f0.z = __uint_as_float(ku.y << 16); f0.w = __uint_as_float(ku.y & 0xffff0000u);
            f1.x = __uint_as_float(ku.z << 16); f1.y = __uint_as_float(ku.z & 0xffff0000u);
            f1.z = __uint_as_float(ku.w << 16); f1.w = __uint_as_float(ku.w & 0xffff0000u);
            *(float4*)&Ksh[r][lc]     = f0;
            *(float4*)&Ksh[r][lc + 4] = f1;
            f0.x = __uint_as_float(vu.x << 16); f0.y = __uint_as_float(vu.x & 0xffff0000u);
            f0.z = __uint_as_float(vu.y << 16); f0.w = __uint_as_float(vu.y & 0xffff0000u);
            f1.x = __uint_as_float(vu.z << 16); f1.y = __uint_as_float(vu.z & 0xffff0000u);
            f1.z = __uint_as_float(vu.w << 16); f1.w = __uint_as_float(vu.w & 0xffff0000u);
            *(float4*)&Vsh[r][lc]     = f0;
            *(float4*)&Vsh[r][lc + 4] = f1;
        }
        __syncthreads();
        float sc[4];
        #pragma unroll
        for (int u = 0; u < 4; ++u) {
            const int kk = tj + 16 * u;
            float s = 0.f;
            #pragma unroll
            for (int d = 0; d < 64; ++d) s = fmaf(qreg[d], Ksh[kk][d], s);
            sc[u] = s;
        }
        float tmax = fmaxf(fmaxf(sc[0], sc[1]), fmaxf(sc[2], sc[3]));
        #pragma unroll
        for (int off = 8; off >= 1; off >>= 1)
            tmax = fmaxf(tmax, __shfl_xor(tmax, off, 16));
        const float mnew = fmaxf(mrun, tmax);
        const float alpha = __expf(mrun - mnew);
        float psum = 0.f;
        #pragma unroll
        for (int u = 0; u < 4; ++u) {
            const float p = __expf(sc[u] - mnew);
            Psh[qi][tj + 16 * u] = p;
            psum += p;
        }
        #pragma unroll
        for (int off = 8; off >= 1; off >>= 1)
            psum += __shfl_xor(psum, off, 16);
        lrunv = lrunv * alpha + psum;
        mrun = mnew;
        oacc[0] *= alpha; oacc[1] *= alpha; oacc[2] *= alpha; oacc[3] *= alpha;
        __syncthreads();
        #pragma unroll 8
        for (int kk = 0; kk < 64; ++kk) {
            const float p = Psh[qi][kk];
            const float4 v4 = *(const float4*)&Vsh[kk][tj * 4];
            oacc[0] = fmaf(p, v4.x, oacc[0]); oacc[1] = fmaf(p, v4.y, oacc[1]);
            oacc[2] = fmaf(p, v4.z, oacc[2]); oacc[3] = fmaf(p, v4.w, oacc[3]);
        }
    }
    const float inv = 1.f / lrunv;
    ushort4 st;
    st.x = f2bf(oacc[0] * inv); st.y = f2bf(oacc[1] * inv);
    st.z = f2bf(oacc[2] * inv); st.w = f2bf(oacc[3] * inv);
    *(ushort4*)(outus + (row0 + s0 + qi) * 2048 + h * 64 + tj * 4) = st;
}

__global__ __launch_bounds__(256)
void out_final(const float* __restrict__ W, const float* __restrict__ bias,
               unsigned short* __restrict__ outus)
{
    float* outf = (float*)outus;
    __shared__ unsigned short Asb[16][1032];
    __shared__ float Bs[16][68];
    const int tid = threadIdx.x;
    const int m0 = blockIdx.x * 16;
    const int tx = tid & 15, ty = tid >> 4;
    #pragma unroll 4
    for (int i = 0; i < 16; ++i)
        *(ushort4*)&Asb[i][tid * 4] =
            *(const ushort4*)(outus + (size_t)(m0 + i) * 2048 + tid * 4);
    __syncthreads();
    for (int n0 = 0; n0 < 1024; n0 += 64) {
        float acc[4] = {0.f, 0.f, 0.f, 0.f};
        for (int k0 = 0; k0 < HID; k0 += 16) {
            *(float4*)&Bs[ty][tx * 4] =
                *(const float4*)(W + (size_t)(k0 + ty) * HID + n0 + tx * 4);
            __syncthreads();
            #pragma unroll
            for (int kk = 0; kk < 16; ++kk) {
                const float a = bf2f(Asb[ty][k0 + kk]);
                const float4 b4 = *(const float4*)&Bs[kk][tx * 4];
                acc[0] = fmaf(a, b4.x, acc[0]); acc[1] = fmaf(a, b4.y, acc[1]);
                acc[2] = fmaf(a, b4.z, acc[2]); acc[3] = fmaf(a, b4.w, acc[3]);
            }
            __syncthreads();
        }
        const int n = n0 + tx * 4;
        float4 st;
        st.x = acc[0] + bias[n + 0]; st.y = acc[1] + bias[n + 1];
        st.z = acc[2] + bias[n + 2]; st.w = acc[3] + bias[n + 3];
        *(float4*)(outf + (size_t)(m0 + ty) * HID + n) = st;
    }
}

// ===========================================================================
extern "C" void kernel_launch(void* const* d_in, const int* in_sizes, int n_in,
                              void* d_out, int out_size, void* d_ws, size_t ws_size,
                              hipStream_t stream) {
    const float* x     = (const float*)d_in[0];
    const float* W_qkv = (const float*)d_in[1];
    const float* b_qkv = (const float*)d_in[2];
    const float* W_out = (const float*)d_in[3];
    const float* b_out = (const float*)d_in[4];

    dim3 blk(256);

    if (ws_size >= (size_t)56 * 1024 * 1024) {
        // qk 32 MB | Vt 16 MB | Wqkv^T 6 MB | Wout^T 2 MB (in d_ws)
        // xb (bf16 x, 16 MB) lives in d_out as scratch until the final GEMM.
        unsigned short* qkbuf  = (unsigned short*)d_ws;
        unsigned short* vtbuf  = qkbuf + (size_t)MTOT * 2048;
        unsigned short* wqkv_t = vtbuf + (size_t)1024 * MTOT;
        unsigned short* wout_t = wqkv_t + (size_t)3072 * 1024;
        unsigned short* xb     = (unsigned short*)d_out;

        cvt_x<<<dim3(MTOT * HID / 1024), blk, 0, stream>>>(x, xb);
        transpose_cvt<<<dim3(3072 / 32, 1024 / 32), blk, 0, stream>>>(
            W_qkv, wqkv_t, 1024, 3072);
        transpose_cvt<<<dim3(1024 / 32, 1024 / 32), blk, 0, stream>>>(
            W_out, wout_t, 1024, 1024);
        // q,k GEMM (N=2048): q scaled, k plain, row-major into qkbuf
        gemm_mfma<false, true, false><<<dim3(2048 / 128, MTOT / 128), blk, 0, stream>>>(
            xb, wqkv_t, b_qkv, (void*)qkbuf, 1024, 2048, 1024);
        // V^T GEMM (swapped operands): Vt[dg][b*2048+s] with coalesced stores
        gemm_mfma<false, false, true><<<dim3(MTOT / 128, 1024 / 128), blk, 0, stream>>>(
            wqkv_t + (size_t)2048 * 1024, xb, b_qkv + 2048, (void*)vtbuf,
            1024, MTOT, 1024);
        // flash attention (flat grid, XCD-grouped); overwrites q-slice of qkbuf
        attn_mfma<<<dim3(512), blk, 0, stream>>>(qkbuf, vtbuf);
        // out-proj (fp32 out, overwrites the d_out scratch)
        gemm_mfma<true, false, false><<<dim3(1024 / 128, MTOT / 128), blk, 0, stream>>>(
            qkbuf, wout_t, b_out, d_out, 2048, 1024, 1024);
    } else {
        // verified round-4 fallback (zero workspace)
        unsigned short* outus = (unsigned short*)d_out;
        unsigned short* xu    = (unsigned short*)d_in[0];
        qproj<<<dim3(HID / 64, MTOT / 64), blk, 0, stream>>>(x, W_qkv, b_qkv, outus);
        kv_inplace<<<dim3(MTOT / 16), blk, 0, stream>>>(W_qkv, b_qkv, xu);
        attn_fwd<<<dim3(SEQ / 16, NH, BATCH), blk, 0, stream>>>(xu, outus);
        out_final<<<dim3(MTOT / 16), blk, 0, stream>>>(W_out, b_out, outus);
    }
}

// Round 9
// 275.073 us; speedup vs baseline: 3.6001x; 1.0046x over previous
//
#include <hip/hip_runtime.h>

// Problem constants: B=4, S=2048, HIDDEN=1024, NH=16, HD=64
#define SEQ    2048
#define BATCH  4
#define HID    1024
#define NH     16
#define MTOT   (BATCH * SEQ)   // 8192

typedef __attribute__((ext_vector_type(8)))  short          short8;   // 8 bf16 frag
typedef __attribute__((ext_vector_type(4)))  float          f32x4;
typedef __attribute__((ext_vector_type(16))) float          f32x16;   // 32x32 C/D
typedef __attribute__((ext_vector_type(8)))  unsigned short ushort8v;
typedef __attribute__((ext_vector_type(4)))  unsigned int   uint4v;

#define QSCL 0.125f   // 1/sqrt(64); __expf supplies the log2e internally

__device__ __forceinline__ float bf2f(unsigned short u) {
    return __uint_as_float(((unsigned int)u) << 16);
}
__device__ __forceinline__ unsigned short f2bf(float f) {
    unsigned int u = __float_as_uint(f);
    u += 0x7fffu + ((u >> 16) & 1u);   // RNE
    return (unsigned short)(u >> 16);
}
// pack two fp32 -> two bf16 (round-half-up) in one uint
__device__ __forceinline__ unsigned int pk2bf(float lo, float hi) {
    unsigned int ul = __float_as_uint(lo) + 0x8000u;
    unsigned int uh = __float_as_uint(hi) + 0x8000u;
    return __builtin_amdgcn_perm(uh, ul, 0x07060302u);
}

// async global->LDS, 16B per lane (global_load_lds_dwordx4)
__device__ __forceinline__ void gl_lds16(const void* g, void* l) {
    __builtin_amdgcn_global_load_lds(
        (__attribute__((address_space(1))) void*)g,
        (__attribute__((address_space(3))) void*)l, 16, 0, 0);
}

// XOR swizzle on 8-element (16B) groups for [*][64] tiles (8 slots/row)
__device__ __forceinline__ int swz64(int row, int col) {
    return row * 64 + ((((col >> 3) ^ (row & 7))) << 3) + (col & 7);
}

// GEMM BK=64 granule layout: granule (row,kq) of a [128][64] bf16 tile at
// ushort offset (row*8 + ((kq + (row&7)) & 7)) * 8.
__device__ __forceinline__ int gidx64(int row, int kq) {
    return (row * 8 + ((kq + (row & 7)) & 7)) * 8;
}

// ===========================================================================
// x fp32 -> bf16 (to d_out scratch). 4 elems/thread.
// ===========================================================================
__global__ __launch_bounds__(256)
void cvt_x(const float* __restrict__ x, unsigned short* __restrict__ xb)
{
    const size_t i = ((size_t)blockIdx.x * 256 + threadIdx.x) * 4;
    const float4 f = *(const float4*)(x + i);
    uint2 u;
    u.x = pk2bf(f.x, f.y);
    u.y = pk2bf(f.z, f.w);
    *(uint2*)(xb + i) = u;
}

// ===========================================================================
// Weight transpose + fp32->bf16: Wt[N][K] = bf16(W[K][N])
// ===========================================================================
__global__ __launch_bounds__(256)
void transpose_cvt(const float* __restrict__ W, unsigned short* __restrict__ Wt,
                   int K, int N)
{
    __shared__ unsigned short T[32][33];
    const int n0 = blockIdx.x * 32, k0 = blockIdx.y * 32;
    const int tr = threadIdx.x >> 3, tc = (threadIdx.x & 7) * 4;
    const float4 f = *(const float4*)(W + (size_t)(k0 + tr) * N + n0 + tc);
    T[tr][tc + 0] = f2bf(f.x);
    T[tr][tc + 1] = f2bf(f.y);
    T[tr][tc + 2] = f2bf(f.z);
    T[tr][tc + 3] = f2bf(f.w);
    __syncthreads();
    ushort4 u;
    u.x = T[tc + 0][tr]; u.y = T[tc + 1][tr];
    u.z = T[tc + 2][tr]; u.w = T[tc + 3][tr];
    *(ushort4*)(Wt + (size_t)(n0 + tr) * K + k0 + tc) = u;
}

// ===========================================================================
// 8-phase 256x256 qk-GEMM (T3+T4 port of the m201 template, plain HIP).
// M=8192, N=2048, K=1024. A=xb[M][1024], Bt=wqkv_t[N][1024], C=qkbuf bf16
// with VSPLIT (col<1024 -> *QSCL).
// Geometry: BK=64, 8 waves (wm=wave>>2 in {0,1}, wn=wave&3 in {0..3}).
// Per-wave frags INTERLEAVED: frag m (0..7) at rows m0+wm*16+m*32+quad*4+rr,
// frag n (0..3) at cols n0+wn*16+n*64+lm. So A-half h holds frags m in
// [h*4,h*4+4), B-half h holds frags n in [h*2,h*2+2) -- each C-quadrant
// Qab = (m-half a, n-half b) needs exactly A-half a + B-half b.
// Phases per K-tile: p0=Q00, p1=Q01, p2=Q10, p3=Q11 (16 MFMA each).
// Stage cadence for tile t+1 during t: p0->A-h0, p1->B-h0, p2->B-h1,
// p3->A-h1 (2 gl_lds16 each). Counted vmcnt(4) at EVERY phase end
// (N = 2 loads/half x 2 halves in flight): age-order proof --
//   t+1 p0 needs A-h0(t,p0)+B-h0(t,p1): youngest 4 = t p2,p3 stages -> ok
//   t+1 p1 needs B-h1(t,p2): youngest 4 = t p3 + t+1 p0 -> ok
//   t+1 p2 needs A-h1(t,p3): youngest 4 = t+1 p0,p1 -> ok
// Last tile (t=15, no stages): vmcnt(0) at phase ends drains leftovers
// before their consumers (B-h1/A-h1 of t=14 read at t15 p1/p2). Raw asm
// s_barrier (NOT __syncthreads -- that drains vmcnt(0) and kills the
// pipeline); asm memory clobbers order the compiler. Buffer-swap safety:
// stage into buf^1 only; all reads of buf complete (per-phase lgkmcnt(0)
// + barriers) before t+1's stages could touch it -- they don't (t+1 stages
// buf). t+2's stages into buf issue after t's last barrier. 2 K-tiles of
// separation => no read/write race.
// Accumulation order per element: K-tiles ascending, kh 0 then 1 --
// IDENTICAL to the 128^2 kernel => bit-identical qk output.
// LDS 128 KB -> 1 block/CU; launch_bounds(512,1) -> 256 VGPR cap (CUDA
// blocks/CU semantics per round-6 finding); kernel needs ~210.
// ===========================================================================
__global__ __launch_bounds__(512, 1)
void gemm_qk8(const unsigned short* __restrict__ A,
              const unsigned short* __restrict__ Bt,
              const float* __restrict__ bias,
              unsigned short* __restrict__ C)
{
    __shared__ unsigned short Asl[2][2][128 * 64];   // [buf][half] 64 KB
    __shared__ unsigned short Bsl[2][2][128 * 64];   // 64 KB

    const int tid  = threadIdx.x;
    const int wave = tid >> 6, lane = tid & 63;
    const int quad = lane >> 4, lm = lane & 15;
    const int wm = wave >> 2, wn = wave & 3;

    // T1 XCD swizzle over 256 blocks (1-D grid): 32 m-tiles x 8 n-tiles
    const int bid = blockIdx.x;
    const int swz = (bid & 7) * 32 + (bid >> 3);
    const int m0 = (swz >> 3) * 256;
    const int n0 = (swz & 7) * 256;

    // staging geometry: 1024 granules/half-tile = 512 thr x 2 issues
    int rowg[2], kqg[2], dofs[2];
#pragma unroll
    for (int j = 0; j < 2; ++j) {
        const int g = (j * 8 + wave) * 64 + lane;
        const int r = g >> 3;
        rowg[j] = r;
        kqg[j]  = (((g & 7) - (r & 7)) & 7) * 8;
        dofs[j] = g * 8;
    }

#define STG_A(BUFD, H, K0)                                                   \
    _Pragma("unroll")                                                        \
    for (int j = 0; j < 2; ++j)                                              \
        gl_lds16(A + (size_t)(m0 + (H) * 128 + rowg[j]) * 1024 + kqg[j] + (K0), \
                 &Asl[BUFD][H][dofs[j]]);
#define STG_B(BUFD, H, K0)                                                   \
    _Pragma("unroll")                                                        \
    for (int j = 0; j < 2; ++j)                                              \
        gl_lds16(Bt + (size_t)(n0 + (H) * 128 + rowg[j]) * 1024 + kqg[j] + (K0), \
                 &Bsl[BUFD][H][dofs[j]]);

    f32x4 acc[8][4];
#pragma unroll
    for (int m = 0; m < 8; ++m)
#pragma unroll
        for (int n = 0; n < 4; ++n)
            acc[m][n] = (f32x4){0.f, 0.f, 0.f, 0.f};

    // fragment LDS offsets (same within each half): i = m&3, j = n&1
    int aOff[4][2], bOff[2][2];
#pragma unroll
    for (int i = 0; i < 4; ++i)
#pragma unroll
        for (int kh = 0; kh < 2; ++kh)
            aOff[i][kh] = gidx64(i * 32 + wm * 16 + lm, kh * 4 + quad);
#pragma unroll
    for (int j = 0; j < 2; ++j)
#pragma unroll
        for (int kh = 0; kh < 2; ++kh)
            bOff[j][kh] = gidx64(j * 64 + wn * 16 + lm, kh * 4 + quad);

    // one phase: quadrant (AH, NB=BH*2) + one half-tile stage
#define PHASE(AH, BH, STAGE_STMT, VMJ)                                       \
    {                                                                        \
        short8 aF[4][2], bF[2][2];                                           \
        _Pragma("unroll")                                                    \
        for (int i = 0; i < 4; ++i)                                          \
            _Pragma("unroll")                                                \
            for (int kh = 0; kh < 2; ++kh)                                   \
                aF[i][kh] = *(const short8*)&Asl[cur][AH][aOff[i][kh]];      \
        _Pragma("unroll")                                                    \
        for (int j = 0; j < 2; ++j)                                          \
            _Pragma("unroll")                                                \
            for (int kh = 0; kh < 2; ++kh)                                   \
                bF[j][kh] = *(const short8*)&Bsl[cur][BH][bOff[j][kh]];      \
        STAGE_STMT                                                           \
        asm volatile("s_barrier" ::: "memory");                              \
        asm volatile("s_waitcnt lgkmcnt(0)" ::: "memory");                   \
        __builtin_amdgcn_s_setprio(1);                                       \
        _Pragma("unroll")                                                    \
        for (int kh = 0; kh < 2; ++kh)                                       \
            _Pragma("unroll")                                                \
            for (int i = 0; i < 4; ++i)                                      \
                _Pragma("unroll")                                            \
                for (int j = 0; j < 2; ++j)                                  \
                    acc[(AH) * 4 + i][(BH) * 2 + j] =                        \
                        __builtin_amdgcn_mfma_f32_16x16x32_bf16(             \
                            aF[i][kh], bF[j][kh],                            \
                            acc[(AH) * 4 + i][(BH) * 2 + j], 0, 0, 0);       \
        __builtin_amdgcn_s_setprio(0);                                       \
        VMJ                                                                  \
        asm volatile("s_barrier" ::: "memory");                              \
    }

#define VM_CNT                                                               \
    if (more) { asm volatile("s_waitcnt vmcnt(4)" ::: "memory"); }           \
    else      { asm volatile("s_waitcnt vmcnt(0)" ::: "memory"); }

    // prologue: tile 0 -> buf 0, age order matching the cadence
    STG_A(0, 0, 0)
    STG_B(0, 0, 0)
    STG_B(0, 1, 0)
    STG_A(0, 1, 0)
    asm volatile("s_waitcnt vmcnt(4)" ::: "memory");   // A-h0 + B-h0 landed
    asm volatile("s_barrier" ::: "memory");

    for (int t = 0; t < 16; ++t) {
        const int cur = t & 1, nxt = cur ^ 1;
        const bool more = (t < 15);
        const int k1 = (t + 1) * 64;

        PHASE(0, 0, if (more) { STG_A(nxt, 0, k1) }, VM_CNT)   // Q00
        PHASE(0, 1, if (more) { STG_B(nxt, 0, k1) }, VM_CNT)   // Q01
        PHASE(1, 0, if (more) { STG_B(nxt, 1, k1) }, VM_CNT)   // Q10
        PHASE(1, 1, if (more) { STG_A(nxt, 1, k1) }, VM_CNT)   // Q11
    }
#undef PHASE
#undef VM_CNT
#undef STG_A
#undef STG_B

    // epilogue: bias + VSPLIT store (same rounding/order as 128^2 kernel)
    float bj[4];
#pragma unroll
    for (int n = 0; n < 4; ++n) bj[n] = bias[n0 + wn * 16 + n * 64 + lm];

#pragma unroll
    for (int m = 0; m < 8; ++m) {
#pragma unroll
        for (int n = 0; n < 4; ++n) {
            const int col = n0 + wn * 16 + n * 64 + lm;
#pragma unroll
            for (int rr = 0; rr < 4; ++rr) {
                const int row = m0 + wm * 16 + m * 32 + quad * 4 + rr;
                float v = acc[m][n][rr] + bj[n];
                if (col < 1024) v *= QSCL;
                C[(size_t)row * 2048 + col] = f2bf(v);
            }
        }
    }
}

// ===========================================================================
// MFMA GEMM, 128x128 tile, BK=64, async global_load_lds staging (v + out).
// T1 XCD swizzle (nwg%8==0: 512/512). BIASROW (v gemm): bias by ROW.
// OUTF32: fp32 C (out-proj).
// ===========================================================================
template<bool OUTF32, bool VSPLIT, bool BIASROW>
__global__ __launch_bounds__(256)
void gemm_mfma(const unsigned short* __restrict__ A,
               const unsigned short* __restrict__ Bt,
               const float* __restrict__ bias, void* __restrict__ Cptr,
               int lda, int ldc, int K)
{
    __shared__ unsigned short As[128 * 64];   // 16 KB
    __shared__ unsigned short Bs[128 * 64];   // 16 KB

    const int tid = threadIdx.x;
    const int wave = tid >> 6, lane = tid & 63;
    const int quad = lane >> 4, lm = lane & 15;
    const int wm = wave & 1, wn = wave >> 1;

    // T1 XCD-aware remap (dispatch is x-fastest; XCD = linear bid % 8)
    const int nwg = gridDim.x * gridDim.y;
    const int bid = blockIdx.y * gridDim.x + blockIdx.x;
    const int swz = (bid & 7) * (nwg >> 3) + (bid >> 3);
    const int m0 = (swz / gridDim.x) * 128;
    const int n0 = (swz % gridDim.x) * 128;

    // staging pointers: 4 granules per thread per matrix per K-step
    const unsigned short* aSrc[4];
    const unsigned short* bSrc[4];
    unsigned short* aDst[4];
    unsigned short* bDst[4];
    #pragma unroll
    for (int j = 0; j < 4; ++j) {
        const int g = (wave * 4 + j) * 64 + lane;   // granule 0..1023
        const int row = g >> 3;
        const int kq = ((g & 7) - (row & 7)) & 7;
        aSrc[j] = A  + (size_t)(m0 + row) * lda + kq * 8;
        bSrc[j] = Bt + (size_t)(n0 + row) * K   + kq * 8;
        aDst[j] = &As[g * 8];
        bDst[j] = &Bs[g * 8];
    }

    f32x4 acc[4][4];
    #pragma unroll
    for (int i = 0; i < 4; ++i)
        #pragma unroll
        for (int j = 0; j < 4; ++j)
            acc[i][j] = (f32x4){0.f, 0.f, 0.f, 0.f};

    // fragment LDS offsets (2 k-halves x 4 tiles), conflict-free
    int aOff[2][4], bOff[2][4];
    #pragma unroll
    for (int h = 0; h < 2; ++h)
        #pragma unroll
        for (int i = 0; i < 4; ++i) {
            aOff[h][i] = gidx64(wm * 64 + i * 16 + lm, h * 4 + quad);
            bOff[h][i] = gidx64(wn * 64 + i * 16 + lm, h * 4 + quad);
        }

    for (int k0 = 0; k0 < K; k0 += 64) {
        __syncthreads();                    // prev consumers done
        #pragma unroll
        for (int j = 0; j < 4; ++j) gl_lds16(aSrc[j] + k0, aDst[j]);
        #pragma unroll
        for (int j = 0; j < 4; ++j) gl_lds16(bSrc[j] + k0, bDst[j]);
        __syncthreads();                    // DMA visible

        #pragma unroll
        for (int h = 0; h < 2; ++h) {
            short8 af[4], bf[4];
            #pragma unroll
            for (int i = 0; i < 4; ++i) af[i] = *(const short8*)&As[aOff[h][i]];
            #pragma unroll
            for (int j = 0; j < 4; ++j) bf[j] = *(const short8*)&Bs[bOff[h][j]];
            #pragma unroll
            for (int i = 0; i < 4; ++i)
                #pragma unroll
                for (int j = 0; j < 4; ++j)
                    acc[i][j] = __builtin_amdgcn_mfma_f32_16x16x32_bf16(
                        af[i], bf[j], acc[i][j], 0, 0, 0);
        }
    }

    float bj[4];        // per-col bias (normal)
    float br[4][4];     // per-row bias (BIASROW): [i][rr]
    if constexpr (BIASROW) {
        #pragma unroll
        for (int i = 0; i < 4; ++i) {
            const float4 t =
                *(const float4*)(bias + m0 + wm * 64 + i * 16 + quad * 4);
            br[i][0] = t.x; br[i][1] = t.y; br[i][2] = t.z; br[i][3] = t.w;
        }
    } else {
        #pragma unroll
        for (int j = 0; j < 4; ++j) bj[j] = bias[n0 + wn * 64 + j * 16 + lm];
    }

    #pragma unroll
    for (int i = 0; i < 4; ++i) {
        #pragma unroll
        for (int j = 0; j < 4; ++j) {
            const int col = n0 + wn * 64 + j * 16 + lm;
            #pragma unroll
            for (int rr = 0; rr < 4; ++rr) {
                const int row = m0 + wm * 64 + i * 16 + quad * 4 + rr;
                float v = acc[i][j][rr] + (BIASROW ? br[i][rr] : bj[j]);
                if constexpr (VSPLIT) {
                    if (col < 1024) v *= QSCL;   // q pre-scale
                    ((unsigned short*)Cptr)[(size_t)row * ldc + col] = f2bf(v);
                } else if constexpr (OUTF32) {
                    ((float*)Cptr)[(size_t)row * ldc + col] = v;
                } else {
                    ((unsigned short*)Cptr)[(size_t)row * ldc + col] = f2bf(v);
                }
            }
        }
    }
}

// ===========================================================================
// MFMA flash attention v9 (round-8 PASS, 96.7 us): KVBLK=64, in-register P
// via T12, gl_lds dbuf staging, T1 XCD grouping (flat grid, qt = bid>>6 so
// the 8 siblings sharing K/V sit on one XCD -> FETCH 139->24.6 MB).
// ===========================================================================
__global__ __launch_bounds__(256, 2)
void attn_mfma(unsigned short* __restrict__ qk,
               const unsigned short* __restrict__ Vt)
{
    const int bid = blockIdx.x;
    const int qt = bid >> 6;          // q-tile (slow dim -> same-XCD siblings)
    const int g  = bid & 63;          // (h,b) group; XCD = g & 7
    const int hh = g & 15;
    const int b  = g >> 4;
    const size_t row0 = (size_t)b * SEQ;
    const int tid = threadIdx.x;
    const int wave = tid >> 6, lane = tid & 63;
    const int l5 = lane >> 5, lm = lane & 31;

    __shared__ unsigned short Ks[2][64 * 64];   // 2 x 8 KB, [kvpos][d] swz64
    __shared__ unsigned short Vs[2][64 * 64];   // 2 x 8 KB, [d][kvpos] swz64

    const int qbase = qt * 256 + wave * 64;

    short8 qf[2][4];
    #pragma unroll
    for (int qg = 0; qg < 2; ++qg)
        #pragma unroll
        for (int ks = 0; ks < 4; ++ks)
            qf[qg][ks] = *(const short8*)(
                qk + (row0 + qbase + qg * 32 + lm) * 2048 + hh * 64 + ks * 16 + l5 * 8);

    f32x16 oacc[2][2];
    #pragma unroll
    for (int dg = 0; dg < 2; ++dg)
        #pragma unroll
        for (int qg = 0; qg < 2; ++qg)
            #pragma unroll
            for (int e = 0; e < 16; ++e) oacc[dg][qg][e] = 0.f;
    float lrun[2] = {0.f, 0.f};

    // DMA staging: 512 granules per matrix per tile = 256 thr x 2 issues.
    const unsigned short* kSrc[2];
    const unsigned short* vSrc[2];
    int dOff[2];
    #pragma unroll
    for (int jj = 0; jj < 2; ++jj) {
        const int gg = (wave * 2 + jj) * 64 + lane;
        const int row = gg >> 3, slot = gg & 7;
        const int colg = slot ^ (row & 7);
        kSrc[jj] = qk + 1024 + hh * 64 + (row0 + row) * 2048 + colg * 8;
        vSrc[jj] = Vt + (size_t)(hh * 64 + row) * (size_t)MTOT
                      + (size_t)b * SEQ + colg * 8;
        dOff[jj] = gg * 8;
    }

    // prologue: stage tile 0 into buffer 0
    #pragma unroll
    for (int jj = 0; jj < 2; ++jj) {
        gl_lds16(kSrc[jj], &Ks[0][dOff[jj]]);
        gl_lds16(vSrc[jj], &Vs[0][dOff[jj]]);
    }
    __syncthreads();   // drains DMA (vmcnt 0) before first reads

    int cur = 0;
    for (int kt = 0; kt < SEQ; kt += 64) {
        if (kt + 64 < SEQ) {   // issue next tile's DMA into the other buffer
            const size_t ko = (size_t)(kt + 64) * 2048;
            const int vo = kt + 64;
            #pragma unroll
            for (int jj = 0; jj < 2; ++jj) {
                gl_lds16(kSrc[jj] + ko, &Ks[cur ^ 1][dOff[jj]]);
                gl_lds16(vSrc[jj] + vo, &Vs[cur ^ 1][dOff[jj]]);
            }
        }
        const unsigned short* ksc = Ks[cur];
        const unsigned short* vsc = Vs[cur];

        #pragma unroll
        for (int kg = 0; kg < 2; ++kg) {
            short8 aK[4];
            #pragma unroll
            for (int ks = 0; ks < 4; ++ks)
                aK[ks] = *(const short8*)&ksc[swz64(kg * 32 + lm, ks * 16 + l5 * 8)];

            // QK^T (swapped: rows = k, cols = q) then exp, all in-register.
            f32x16 s[2];
            #pragma unroll
            for (int qg = 0; qg < 2; ++qg) {
                #pragma unroll
                for (int e = 0; e < 16; ++e) s[qg][e] = 0.f;
                __builtin_amdgcn_s_setprio(1);
                #pragma unroll
                for (int ks = 0; ks < 4; ++ks)
                    s[qg] = __builtin_amdgcn_mfma_f32_32x32x16_bf16(
                        aK[ks], qf[qg][ks], s[qg], 0, 0, 0);
                __builtin_amdgcn_s_setprio(0);
                float ls = 0.f;
                #pragma unroll
                for (int rg = 0; rg < 4; ++rg) {
                    const float p0 = __expf(s[qg][rg * 4 + 0]);
                    const float p1 = __expf(s[qg][rg * 4 + 1]);
                    const float p2 = __expf(s[qg][rg * 4 + 2]);
                    const float p3 = __expf(s[qg][rg * 4 + 3]);
                    s[qg][rg * 4 + 0] = p0; s[qg][rg * 4 + 1] = p1;
                    s[qg][rg * 4 + 2] = p2; s[qg][rg * 4 + 3] = p3;
                    ls += (p0 + p1) + (p2 + p3);
                }
                lrun[qg] += ls;
            }

            // PV: build B-fragment in-register (T12).
            #pragma unroll
            for (int step = 0; step < 2; ++step) {
                const int ks = kg * 2 + step;
                const short8 aV0 =
                    *(const short8*)&vsc[swz64(lm,      ks * 16 + l5 * 8)];
                const short8 aV1 =
                    *(const short8*)&vsc[swz64(32 + lm, ks * 16 + l5 * 8)];
                #pragma unroll
                for (int qg = 0; qg < 2; ++qg) {
                    const int b0 = step * 8;
                    const unsigned int u  = pk2bf(s[qg][b0 + 0], s[qg][b0 + 1]);
                    const unsigned int vv = pk2bf(s[qg][b0 + 2], s[qg][b0 + 3]);
                    const unsigned int u2 = pk2bf(s[qg][b0 + 4], s[qg][b0 + 5]);
                    const unsigned int v2 = pk2bf(s[qg][b0 + 6], s[qg][b0 + 7]);
                    const auto rA =
                        __builtin_amdgcn_permlane32_swap(u,  u2, false, false);
                    const auto rB =
                        __builtin_amdgcn_permlane32_swap(vv, v2, false, false);
                    uint4v wv;
                    wv.x = rA[0]; wv.y = rB[0]; wv.z = rA[1]; wv.w = rB[1];
                    const short8 bP = __builtin_bit_cast(short8, wv);
                    __builtin_amdgcn_s_setprio(1);
                    oacc[0][qg] = __builtin_amdgcn_mfma_f32_32x32x16_bf16(
                        aV0, bP, oacc[0][qg], 0, 0, 0);
                    oacc[1][qg] = __builtin_amdgcn_mfma_f32_32x32x16_bf16(
                        aV1, bP, oacc[1][qg], 0, 0, 0);
                    __builtin_amdgcn_s_setprio(0);
                }
            }
        }
        __syncthreads();   // readers of cur done; next-tile DMA drained (vmcnt 0)
        cur ^= 1;
    }

    float linv[2];
    #pragma unroll
    for (int qg = 0; qg < 2; ++qg) {
        const float lt = lrun[qg] + __shfl_xor(lrun[qg], 32);
        linv[qg] = 1.f / lt;
    }

    #pragma unroll
    for (int dg = 0; dg < 2; ++dg)
        #pragma unroll
        for (int qg = 0; qg < 2; ++qg) {
            unsigned short* orow =
                qk + (row0 + qbase + qg * 32 + lm) * 2048 + hh * 64;
            #pragma unroll
            for (int rg = 0; rg < 4; ++rg) {
                const int d0 = dg * 32 + rg * 8 + l5 * 4;
                ushort4 st;
                st.x = f2bf(oacc[dg][qg][rg * 4 + 0] * linv[qg]);
                st.y = f2bf(oacc[dg][qg][rg * 4 + 1] * linv[qg]);
                st.z = f2bf(oacc[dg][qg][rg * 4 + 2] * linv[qg]);
                st.w = f2bf(oacc[dg][qg][rg * 4 + 3] * linv[qg]);
                *(ushort4*)(orow + d0) = st;
            }
        }
}

// ===========================================================================
// ================= FALLBACK PATH (round-4, verified PASS) ==================
// ===========================================================================
__global__ __launch_bounds__(256)
void qproj(const float* __restrict__ A, const float* __restrict__ W,
           const float* __restrict__ bias, unsigned short* __restrict__ outus)
{
    __shared__ float As[64][17];
    __shared__ float Bs[16][64];
    const int tid = threadIdx.x;
    const int tx = tid & 15, ty = tid >> 4;
    const int m0 = blockIdx.y * 64, n0 = blockIdx.x * 64;
    const int ar = tid >> 2, ac = (tid & 3) * 4;
    const int br = tid >> 4, bc = (tid & 15) * 4;
    float acc[4][4] = {{0.f}};
    for (int k0 = 0; k0 < HID; k0 += 16) {
        const float4 av = *(const float4*)(A + (size_t)(m0 + ar) * HID + k0 + ac);
        As[ar][ac + 0] = av.x; As[ar][ac + 1] = av.y;
        As[ar][ac + 2] = av.z; As[ar][ac + 3] = av.w;
        *(float4*)&Bs[br][bc] =
            *(const float4*)(W + (size_t)(k0 + br) * 3072 + n0 + bc);
        __syncthreads();
        #pragma unroll
        for (int kk = 0; kk < 16; ++kk) {
            float a[4];
            #pragma unroll
            for (int i = 0; i < 4; ++i) a[i] = As[ty * 4 + i][kk];
            const float4 b4 = *(const float4*)&Bs[kk][tx * 4];
            const float bv[4] = {b4.x, b4.y, b4.z, b4.w};
            #pragma unroll
            for (int i = 0; i < 4; ++i)
                #pragma unroll
                for (int j = 0; j < 4; ++j)
                    acc[i][j] = fmaf(a[i], bv[j], acc[i][j]);
        }
        __syncthreads();
    }
    float bb[4];
    #pragma unroll
    for (int j = 0; j < 4; ++j) bb[j] = bias[n0 + tx * 4 + j];
    #pragma unroll
    for (int i = 0; i < 4; ++i) {
        ushort4 st;
        st.x = f2bf(acc[i][0] + bb[0]); st.y = f2bf(acc[i][1] + bb[1]);
        st.z = f2bf(acc[i][2] + bb[2]); st.w = f2bf(acc[i][3] + bb[3]);
        *(ushort4*)(outus + (size_t)(m0 + ty * 4 + i) * 2048 + 1024 + n0 + tx * 4) = st;
    }
}

__global__ __launch_bounds__(256)
void kv_inplace(const float* __restrict__ W, const float* __restrict__ bias,
                unsigned short* __restrict__ xu)
{
    const float* xf = (const float*)xu;
    __shared__ unsigned short Asb[16][1032];
    __shared__ float Bs[16][68];
    const int tid = threadIdx.x;
    const int m0 = blockIdx.x * 16;
    const int tx = tid & 15, ty = tid >> 4;
    #pragma unroll 4
    for (int i = 0; i < 16; ++i) {
        const float4 v = *(const float4*)(xf + (size_t)(m0 + i) * HID + tid * 4);
        ushort4 s;
        s.x = f2bf(v.x); s.y = f2bf(v.y); s.z = f2bf(v.z); s.w = f2bf(v.w);
        *(ushort4*)&Asb[i][tid * 4] = s;
    }
    __syncthreads();
    for (int n0 = 0; n0 < 2048; n0 += 64) {
        float acc[4] = {0.f, 0.f, 0.f, 0.f};
        for (int k0 = 0; k0 < HID; k0 += 16) {
            *(float4*)&Bs[ty][tx * 4] =
                *(const float4*)(W + (size_t)(k0 + ty) * 3072 + 1024 + n0 + tx * 4);
            __syncthreads();
            #pragma unroll
            for (int kk = 0; kk < 16; ++kk) {
                const float a = bf2f(Asb[ty][k0 + kk]);
                const float4 b4 = *(const float4*)&Bs[kk][tx * 4];
                acc[0] = fmaf(a, b4.x, acc[0]); acc[1] = fmaf(a, b4.y, acc[1]);
                acc[2] = fmaf(a, b4.z, acc[2]); acc[3] = fmaf(a, b4.w, acc[3]);
            }
            __syncthreads();
        }
        const int n = n0 + tx * 4;
        ushort4 s;
        s.x = f2bf(acc[0] + bias[1024 + n + 0]);
        s.y = f2bf(acc[1] + bias[1024 + n + 1]);
        s.z = f2bf(acc[2] + bias[1024 + n + 2]);
        s.w = f2bf(acc[3] + bias[1024 + n + 3]);
        *(ushort4*)(xu + (size_t)(m0 + ty) * 2048 + n) = s;
    }
}

__global__ __launch_bounds__(256)
void attn_fwd(const unsigned short* __restrict__ xu,
              unsigned short* __restrict__ outus)
{
    const int qt = blockIdx.x, h = blockIdx.y, b = blockIdx.z;
    const int s0 = qt * 16;
    const size_t row0 = (size_t)b * SEQ;
    const int tid = threadIdx.x;
    const int qi = tid >> 4, tj = tid & 15;
    __shared__ float Ksh[64][68];
    __shared__ float Vsh[64][68];
    __shared__ float Psh[16][68];
    float qreg[64];
    {
        const uint4* qp =
            (const uint4*)(outus + (row0 + s0 + qi) * 2048 + 1024 + h * 64);
        #pragma unroll
        for (int i = 0; i < 8; ++i) {
            uint4 u = qp[i];
            const unsigned int w[4] = {u.x, u.y, u.z, u.w};
            #pragma unroll
            for (int j = 0; j < 4; ++j) {
                qreg[i * 8 + j * 2 + 0] = __uint_as_float(w[j] << 16) * 0.125f;
                qreg[i * 8 + j * 2 + 1] = __uint_as_float(w[j] & 0xffff0000u) * 0.125f;
            }
        }
    }
    float mrun = -1e30f, lrunv = 0.f;
    float oacc[4] = {0.f, 0.f, 0.f, 0.f};
    const int lr = tid >> 3, lc = (tid & 7) * 8;
    for (int kt = 0; kt < SEQ; kt += 64) {
        __syncthreads();
        #pragma unroll
        for (int half = 0; half < 2; ++half) {
            const int r = lr + half * 32;
            const size_t rowoff = (row0 + kt + r) * 2048 + h * 64 + lc;
            uint4 ku = *(const uint4*)(xu + rowoff);
            uint4 vu = *(const uint4*)(xu + rowoff + 1024);
            float4 f0, f1;
            f0.x = __uint_as_float(ku.x << 16); f0.y = __uint_as_float(ku.x & 0xffff0000u);
            f0.z = __uint_as_float(ku.y << 16); f0.w = __uint_as_float(ku.y & 0xffff0000u);
            f1.x = __uint_as_float(ku.z << 16); f1.y = __uint_as_float(ku.z & 0xffff0000u);
            f1.z = __uint_as_float(ku.w << 16); f1.w = __uint_as_float(ku.w & 0xffff0000u);
            *(float4*)&Ksh[r][lc]     = f0;
            *(float4*)&Ksh[r][lc + 4] = f1;
            f0.x = __uint_as_float(vu.x << 16); f0.y = __uint_as_float(vu.x & 0xffff0000u);
            f0.z = __uint_as_float(vu.y << 16); f0.w = __uint_as_float(vu.y & 0xffff0000u);
            f1.x = __uint_as_float(vu.z << 16); f1.y = __uint_as_float(vu.z & 0xffff0000u);
            f1.z = __uint_as_float(vu.w << 16); f1.w = __uint_as_float(vu.w & 0xffff0000u);
            *(float4*)&Vsh[r][lc]     = f0;
            *(float4*)&Vsh[r][lc + 4] = f1;
        }
        __syncthreads();
        float sc[4];
        #pragma unroll
        for (int u = 0; u < 4; ++u) {
            const int kk = tj + 16 * u;
            float s = 0.f;
            #pragma unroll
            for (int d = 0; d < 64; ++d) s = fmaf(qreg[d], Ksh[kk][d], s);
            sc[u] = s;
        }
        float tmax = fmaxf(fmaxf(sc[0], sc[1]), fmaxf(sc[2], sc[3]));
        #pragma unroll
        for (int off = 8; off >= 1; off >>= 1)
            tmax = fmaxf(tmax, __shfl_xor(tmax, off, 16));
        const float mnew = fmaxf(mrun, tmax);
        const float alpha = __expf(mrun - mnew);
        float psum = 0.f;
        #pragma unroll
        for (int u = 0; u < 4; ++u) {
            const float p = __expf(sc[u] - mnew);
            Psh[qi][tj + 16 * u] = p;
            psum += p;
        }
        #pragma unroll
        for (int off = 8; off >= 1; off >>= 1)
            psum += __shfl_xor(psum, off, 16);
        lrunv = lrunv * alpha + psum;
        mrun = mnew;
        oacc[0] *= alpha; oacc[1] *= alpha; oacc[2] *= alpha; oacc[3] *= alpha;
        __syncthreads();
        #pragma unroll 8
        for (int kk = 0; kk < 64; ++kk) {
            const float p = Psh[qi][kk];
            const float4 v4 = *(const float4*)&Vsh[kk][tj * 4];
            oacc[0] = fmaf(p, v4.x, oacc[0]); oacc[1] = fmaf(p, v4.y, oacc[1]);
            oacc[2] = fmaf(p, v4.z, oacc[2]); oacc[3] = fmaf(p, v4.w, oacc[3]);
        }
    }
    const float inv = 1.f / lrunv;
    ushort4 st;
    st.x = f2bf(oacc[0] * inv); st.y = f2bf(oacc[1] * inv);
    st.z = f2bf(oacc[2] * inv); st.w = f2bf(oacc[3] * inv);
    *(ushort4*)(outus + (row0 + s0 + qi) * 2048 + h * 64 + tj * 4) = st;
}

__global__ __launch_bounds__(256)
void out_final(const float* __restrict__ W, const float* __restrict__ bias,
               unsigned short* __restrict__ outus)
{
    float* outf = (float*)outus;
    __shared__ unsigned short Asb[16][1032];
    __shared__ float Bs[16][68];
    const int tid = threadIdx.x;
    const int m0 = blockIdx.x * 16;
    const int tx = tid & 15, ty = tid >> 4;
    #pragma unroll 4
    for (int i = 0; i < 16; ++i)
        *(ushort4*)&Asb[i][tid * 4] =
            *(const ushort4*)(outus + (size_t)(m0 + i) * 2048 + tid * 4);
    __syncthreads();
    for (int n0 = 0; n0 < 1024; n0 += 64) {
        float acc[4] = {0.f, 0.f, 0.f, 0.f};
        for (int k0 = 0; k0 < HID; k0 += 16) {
            *(float4*)&Bs[ty][tx * 4] =
                *(const float4*)(W + (size_t)(k0 + ty) * HID + n0 + tx * 4);
            __syncthreads();
            #pragma unroll
            for (int kk = 0; kk < 16; ++kk) {
                const float a = bf2f(Asb[ty][k0 + kk]);
                const float4 b4 = *(const float4*)&Bs[kk][tx * 4];
                acc[0] = fmaf(a, b4.x, acc[0]); acc[1] = fmaf(a, b4.y, acc[1]);
                acc[2] = fmaf(a, b4.z, acc[2]); acc[3] = fmaf(a, b4.w, acc[3]);
            }
            __syncthreads();
        }
        const int n = n0 + tx * 4;
        float4 st;
        st.x = acc[0] + bias[n + 0]; st.y = acc[1] + bias[n + 1];
        st.z = acc[2] + bias[n + 2]; st.w = acc[3] + bias[n + 3];
        *(float4*)(outf + (size_t)(m0 + ty) * HID + n) = st;
    }
}

// ===========================================================================
extern "C" void kernel_launch(void* const* d_in, const int* in_sizes, int n_in,
                              void* d_out, int out_size, void* d_ws, size_t ws_size,
                              hipStream_t stream) {
    const float* x     = (const float*)d_in[0];
    const float* W_qkv = (const float*)d_in[1];
    const float* b_qkv = (const float*)d_in[2];
    const float* W_out = (const float*)d_in[3];
    const float* b_out = (const float*)d_in[4];

    dim3 blk(256);

    if (ws_size >= (size_t)56 * 1024 * 1024) {
        // qk 32 MB | Vt 16 MB | Wqkv^T 6 MB | Wout^T 2 MB (in d_ws)
        // xb (bf16 x, 16 MB) lives in d_out as scratch until the final GEMM.
        unsigned short* qkbuf  = (unsigned short*)d_ws;
        unsigned short* vtbuf  = qkbuf + (size_t)MTOT * 2048;
        unsigned short* wqkv_t = vtbuf + (size_t)1024 * MTOT;
        unsigned short* wout_t = wqkv_t + (size_t)3072 * 1024;
        unsigned short* xb     = (unsigned short*)d_out;

        cvt_x<<<dim3(MTOT * HID / 1024), blk, 0, stream>>>(x, xb);
        transpose_cvt<<<dim3(3072 / 32, 1024 / 32), blk, 0, stream>>>(
            W_qkv, wqkv_t, 1024, 3072);
        transpose_cvt<<<dim3(1024 / 32, 1024 / 32), blk, 0, stream>>>(
            W_out, wout_t, 1024, 1024);
        // q,k GEMM (N=2048): 8-phase 256^2 template, q scaled, k plain
        gemm_qk8<<<dim3(256), dim3(512), 0, stream>>>(
            xb, wqkv_t, b_qkv, qkbuf);
        // V^T GEMM (swapped operands): Vt[dg][b*2048+s] with coalesced stores
        gemm_mfma<false, false, true><<<dim3(MTOT / 128, 1024 / 128), blk, 0, stream>>>(
            wqkv_t + (size_t)2048 * 1024, xb, b_qkv + 2048, (void*)vtbuf,
            1024, MTOT, 1024);
        // flash attention (flat grid, XCD-grouped); overwrites q-slice of qkbuf
        attn_mfma<<<dim3(512), blk, 0, stream>>>(qkbuf, vtbuf);
        // out-proj (fp32 out, overwrites the d_out scratch)
        gemm_mfma<true, false, false><<<dim3(1024 / 128, MTOT / 128), blk, 0, stream>>>(
            qkbuf, wout_t, b_out, d_out, 2048, 1024, 1024);
    } else {
        // verified round-4 fallback (zero workspace)
        unsigned short* outus = (unsigned short*)d_out;
        unsigned short* xu    = (unsigned short*)d_in[0];
        qproj<<<dim3(HID / 64, MTOT / 64), blk, 0, stream>>>(x, W_qkv, b_qkv, outus);
        kv_inplace<<<dim3(MTOT / 16), blk, 0, stream>>>(W_qkv, b_qkv, xu);
        attn_fwd<<<dim3(SEQ / 16, NH, BATCH), blk, 0, stream>>>(xu, outus);
        out_final<<<dim3(MTOT / 16), blk, 0, stream>>>(W_out, b_out, outus);
    }
}